// Round 3
// baseline (3604.850 us; speedup 1.0000x reference)
//
#include <hip/hip_runtime.h>
#include <hip/hip_bf16.h>
#include <stdint.h>

#define DINL __device__ __forceinline__

DINL float bf2f(__hip_bfloat16 v) { return __bfloat162float(v); }
DINL __hip_bfloat16 f2bf(float v) { return __float2bfloat16(v); }
DINL float bflo(unsigned int u) { return __uint_as_float(u << 16); }
DINL float bfhi(unsigned int u) { return __uint_as_float(u & 0xffff0000u); }

DINL float loadf(float v) { return v; }
DINL float loadf(__hip_bfloat16 v) { return __bfloat162float(v); }

// ---------------- ws layout ----------------
// fp32 region (float offsets):
#define O_WTE1 0         // [2][3][9][32]      1728
#define O_WTE2 2048      // [4][64][9][32]     73728
#define O_WG1  75776     // [2][128][9][32]    73728
#define O_WF1  149504    // [8][128][9][32]    294912
#define O_WF2  444416    // [1176][256]        301056
#define O_WG2  745472    // [6][64]            384
#define O_S    745984    // [4][8][9][32]      9216
#define O_INT  755200    // [4][16384]         65536
// byte offsets:
#define BO_TEX  4194304u    // tex bf16 [4][128][128][128]  16.78 MB
#define BO_F1   20971520u   // f1 bf16 pixel-major [4][16384][256]  33.55 MB
#define BO_PING 54525952u   // fp32 [4*24*16384]  6.29 MB
#define BO_PONG 60817408u
#define BO_W    67108864u   // weights bf16 [4][24][49][16384]  154.14 MB
#define BO_T1   BO_W            // t1 bf16 (dead before W written)
#define BO_G1   (BO_W + 16777216u)  // g1 bf16 (dead before W written)

// ---------------- prep: re-layout weights (block layout) + S table ----------------
__global__ __launch_bounds__(256) void prep_kernel(
    const float* __restrict__ w_te1, const float* __restrict__ w_te2,
    const float* __restrict__ w_g1,  const float* __restrict__ w_f1,
    const float* __restrict__ w_f2,  const float* __restrict__ w_g2,
    const float* __restrict__ emb,   const int* __restrict__ labels,
    float* __restrict__ wsf)
{
  const int gid = blockIdx.x * 256 + threadIdx.x;
  const int stride = gridDim.x * 256;
  const int N1 = 1728, N2 = N1 + 73728, N3 = N2 + 73728, N4 = N3 + 294912,
            N5 = N4 + 301056, N6 = N5 + 384;
  for (int i = gid; i < N6; i += stride) {
    if (i < N1) {
      int s = i; int o = s / 27; int r = s - o * 27; int ic = r / 9; int t = r - ic * 9;
      wsf[O_WTE1 + (((o >> 5) * 3 + ic) * 9 + t) * 32 + (o & 31)] = w_te1[s];
    } else if (i < N2) {
      int s = i - N1; int o = s / 576; int r = s - o * 576; int ic = r / 9; int t = r - ic * 9;
      wsf[O_WTE2 + (((o >> 5) * 64 + ic) * 9 + t) * 32 + (o & 31)] = w_te2[s];
    } else if (i < N3) {
      int s = i - N2; int o = s / 1152; int r = s - o * 1152; int ic = r / 9; int t = r - ic * 9;
      wsf[O_WG1 + (((o >> 5) * 128 + ic) * 9 + t) * 32 + (o & 31)] = w_g1[s];
    } else if (i < N4) {
      int s = i - N3; int o = s / 1152; int r = s - o * 1152; int ic = r / 9; int t = r - ic * 9;
      wsf[O_WF1 + (((o >> 5) * 128 + ic) * 9 + t) * 32 + (o & 31)] = w_f1[o * 2304 + r];
    } else if (i < N5) {
      int s = i - N4;
      wsf[O_WF2 + s] = w_f2[s];
    } else {
      int s = i - N5;
      wsf[O_WG2 + s] = w_g2[s];
    }
  }
  // S[b][o][t] = sum_i w_f1[o][128+i][t] * emb[label_b][i]   (emb half of fusion conv1)
  if (gid < 9216) {
    int b = gid / 2304; int r = gid - b * 2304; int o = r / 9; int t = r - o * 9;
    int lab = labels[b];
    float sum = 0.f;
    for (int i = 0; i < 128; ++i)
      sum += w_f1[o * 2304 + (128 + i) * 9 + t] * emb[lab * 128 + i];
    wsf[O_S + b * 2304 + (o >> 5) * 288 + t * 32 + (o & 31)] = sum;
  }
}

// ---------------- generic 3x3 conv (zero pad), fp32 acc, ReLU ----------------
// weights fp32 layout [och/32][ICH][9][32]; 16x16 pixel tile; 32 och per block.
template<typename TIn, int ICH, bool ADD_S, bool PIXMAJOR>
__global__ __launch_bounds__(256) void conv3x3_kernel(
    const TIn* __restrict__ in, const float* __restrict__ wf,
    const float* __restrict__ bias, const float* __restrict__ S,
    __hip_bfloat16* __restrict__ out, const int och_total)
{
  constexpr int CH = (ICH < 16) ? ICH : 16;
  constexpr int NCHUNK = ICH / CH;
  __shared__ TIn sIn[CH][18][20];
  const int tid = threadIdx.x;
  const int b = blockIdx.z;
  const int ob = blockIdx.y;
  const int och0 = ob * 32;
  const int tileY = blockIdx.x >> 3, tileX = blockIdx.x & 7;
  const int ty = tid >> 4, tx = tid & 15;
  const int h = tileY * 16 + ty, w = tileX * 16 + tx;
  const int h0 = tileY * 16 - 1, w0 = tileX * 16 - 1;

  float acc[32];
#pragma unroll
  for (int o = 0; o < 32; ++o) acc[o] = bias[och0 + o];

  for (int cc = 0; cc < NCHUNK; ++cc) {
    if (cc) __syncthreads();
    for (int e = tid; e < CH * 324; e += 256) {
      int ic = e / 324, r = e - ic * 324;
      int y = r / 18, x = r - y * 18;
      int gh = h0 + y, gw = w0 + x;
      TIn v = TIn(0.f);
      if ((unsigned)gh < 128u && (unsigned)gw < 128u)
        v = in[((b * ICH + cc * CH + ic) << 14) + (gh << 7) + gw];
      sIn[ic][y][x] = v;
    }
    __syncthreads();
#pragma unroll 1
    for (int ic = 0; ic < CH; ++ic) {
      const float* wrow = wf + (ob * ICH + cc * CH + ic) * 288;  // [9][32]
#pragma unroll
      for (int t = 0; t < 9; ++t) {
        const int kh = t / 3, kw = t - kh * 3;
        const float v = loadf(sIn[ic][ty + kh][tx + kw]);
#pragma unroll
        for (int o = 0; o < 32; ++o)
          acc[o] = fmaf(wrow[t * 32 + o], v, acc[o]);
      }
    }
  }

  if constexpr (ADD_S) {
    // spatially-constant emb contribution, masked by zero-pad tap validity
    const float* Sp = S + b * 2304 + ob * 288;
#pragma unroll
    for (int t = 0; t < 9; ++t) {
      const int kh = t / 3, kw = t - kh * 3;
      const bool vh = (kh == 1) ? true : (kh == 0 ? (h > 0) : (h < 127));
      const bool vw = (kw == 1) ? true : (kw == 0 ? (w > 0) : (w < 127));
      const float msk = (vh && vw) ? 1.f : 0.f;
#pragma unroll
      for (int o = 0; o < 32; ++o)
        acc[o] = fmaf(msk, Sp[t * 32 + o], acc[o]);
    }
  }

  const int pix = (h << 7) + w;
  if constexpr (!PIXMAJOR) {
#pragma unroll
    for (int o = 0; o < 32; ++o)
      out[((b * och_total + och0 + o) << 14) + pix] = f2bf(fmaxf(acc[o], 0.f));
  } else {
    union { uint4 u4[4]; __hip_bfloat16 hh[32]; } pk;
#pragma unroll
    for (int o = 0; o < 32; ++o) pk.hh[o] = f2bf(fmaxf(acc[o], 0.f));
    uint4* dst = reinterpret_cast<uint4*>(out + ((size_t)(b << 14) + pix) * och_total + och0);
#pragma unroll
    for (int i = 0; i < 4; ++i) dst[i] = pk.u4[i];
  }
}

// ---------------- gate 1x1 conv + sigmoid + class_gate / intensity / condition_map ----------------
__global__ __launch_bounds__(256) void gate2_kernel(
    const __hip_bfloat16* __restrict__ g1, const float* __restrict__ wg2,
    const float* __restrict__ b_g2, const int* __restrict__ labels,
    const float* __restrict__ ci,
    float* __restrict__ out_cg, float* __restrict__ out_cond,
    float* __restrict__ inten)
{
  const int b = blockIdx.y;
  const int pix = blockIdx.x * 256 + threadIdx.x;
  float acc[6];
#pragma unroll
  for (int k = 0; k < 6; ++k) acc[k] = b_g2[k];
  for (int i = 0; i < 64; ++i) {
    float v = bf2f(g1[((b * 64 + i) << 14) + pix]);
#pragma unroll
    for (int k = 0; k < 6; ++k) acc[k] = fmaf(wg2[k * 64 + i], v, acc[k]);
  }
  const int lab = labels[b];
  float gate[6], gl = 0.f;
#pragma unroll
  for (int k = 0; k < 6; ++k) {
    gate[k] = 1.f / (1.f + __expf(-acc[k]));
    gl = (k == lab) ? gate[k] : gl;
  }
  const float civ = ci[lab];
  const float it = gl * civ;
#pragma unroll
  for (int k = 0; k < 6; ++k)
    out_cg[((b * 6 + k) << 14) + pix] = (k == lab) ? gate[k] : 0.f;
  inten[(b << 14) + pix] = it;
  out_cond[(b << 14) + pix] = it * gl;
}

// ---------------- fusion 1x1 conv (256->1176) + intensity scale + softmax(49) -> bf16 weights ----------------
__global__ __launch_bounds__(256) void conv1x1_softmax_kernel(
    const __hip_bfloat16* __restrict__ f1, const float* __restrict__ wf2,
    const float* __restrict__ b_f2, const float* __restrict__ inten,
    __hip_bfloat16* __restrict__ wout)
{
  const int b = blockIdx.z;
  const int c0 = blockIdx.y * 12;
  const int pix = blockIdx.x * 256 + threadIdx.x;
  const float s = inten[(b << 14) + pix];
  const uint4* fin = reinterpret_cast<const uint4*>(f1) + (((size_t)(b << 14) + pix) << 5);
  for (int cl = 0; cl < 12; ++cl) {
    const int c = c0 + cl;
    const float* wp = wf2 + (size_t)c * 49 * 256;
    float acc[49];
#pragma unroll
    for (int t = 0; t < 49; ++t) acc[t] = b_f2[c * 49 + t];
#pragma unroll 1
    for (int i4 = 0; i4 < 32; ++i4) {
      const uint4 q = fin[i4];
      const float v0 = bflo(q.x), v1 = bfhi(q.x), v2 = bflo(q.y), v3 = bfhi(q.y);
      const float v4 = bflo(q.z), v5 = bfhi(q.z), v6 = bflo(q.w), v7 = bfhi(q.w);
      const float* wq = wp + i4 * 8;
#pragma unroll
      for (int t = 0; t < 49; ++t) {
        const float* w8 = wq + t * 256;
        acc[t] = fmaf(w8[0], v0, acc[t]); acc[t] = fmaf(w8[1], v1, acc[t]);
        acc[t] = fmaf(w8[2], v2, acc[t]); acc[t] = fmaf(w8[3], v3, acc[t]);
        acc[t] = fmaf(w8[4], v4, acc[t]); acc[t] = fmaf(w8[5], v5, acc[t]);
        acc[t] = fmaf(w8[6], v6, acc[t]); acc[t] = fmaf(w8[7], v7, acc[t]);
      }
    }
    float m = -3.4e38f;
#pragma unroll
    for (int t = 0; t < 49; ++t) { acc[t] *= s; m = fmaxf(m, acc[t]); }
    float sum = 0.f;
#pragma unroll
    for (int t = 0; t < 49; ++t) { acc[t] = __expf(acc[t] - m); sum += acc[t]; }
    const float r = 1.f / sum;
    __hip_bfloat16* wo = wout + (((size_t)(b * 24 + c) * 49) << 14) + pix;
#pragma unroll
    for (int t = 0; t < 49; ++t) wo[(size_t)t << 14] = f2bf(acc[t] * r);
  }
}

// ---------------- one diffusion step: per-pixel 7x7 weighted average, edge-clamped ----------------
__global__ __launch_bounds__(256) void diff_kernel(
    const float* __restrict__ lin, const __hip_bfloat16* __restrict__ wts,
    float* __restrict__ lout)
{
  __shared__ float sT[10][70];   // 4+6 rows, 64+6 cols
  const int bc = blockIdx.z;
  const int w0 = blockIdx.x * 64, h0 = blockIdx.y * 4;
  const int tid = threadIdx.y * 64 + threadIdx.x;
  for (int e = tid; e < 700; e += 256) {
    int y = e / 70, x = e - y * 70;
    int gh = min(max(h0 - 3 + y, 0), 127), gw = min(max(w0 - 3 + x, 0), 127);
    sT[y][x] = lin[(bc << 14) + (gh << 7) + gw];
  }
  __syncthreads();
  const int tx = threadIdx.x, ty = threadIdx.y;
  const int pix = ((h0 + ty) << 7) + w0 + tx;
  const __hip_bfloat16* wp = wts + (((size_t)bc * 49) << 14) + pix;
  float acc = 0.f;
#pragma unroll
  for (int t = 0; t < 49; ++t) {
    const int kh = t / 7, kw = t - kh * 7;
    acc = fmaf(bf2f(wp[(size_t)t << 14]), sT[ty + kh][tx + kw], acc);
  }
  lout[(bc << 14) + pix] = acc;
}

// ---------------- orchestration ----------------
extern "C" void kernel_launch(void* const* d_in, const int* in_sizes, int n_in,
                              void* d_out, int out_size, void* d_ws, size_t ws_size,
                              hipStream_t stream)
{
  const float* depth = (const float*)d_in[0];
  const float* texf  = (const float*)d_in[1];
  const int*   labels= (const int*)d_in[2];
  const float* w_te1 = (const float*)d_in[3];
  const float* b_te1 = (const float*)d_in[4];
  const float* w_te2 = (const float*)d_in[5];
  const float* b_te2 = (const float*)d_in[6];
  const float* emb   = (const float*)d_in[7];
  const float* w_f1  = (const float*)d_in[8];
  const float* b_f1  = (const float*)d_in[9];
  const float* w_f2  = (const float*)d_in[10];
  const float* b_f2  = (const float*)d_in[11];
  const float* w_g1  = (const float*)d_in[12];
  const float* b_g1  = (const float*)d_in[13];
  const float* w_g2  = (const float*)d_in[14];
  const float* b_g2  = (const float*)d_in[15];
  const float* ci    = (const float*)d_in[16];

  char*  ws  = (char*)d_ws;
  float* wsf = (float*)d_ws;
  __hip_bfloat16* tex  = (__hip_bfloat16*)(ws + BO_TEX);
  __hip_bfloat16* f1   = (__hip_bfloat16*)(ws + BO_F1);
  float* ping          = (float*)(ws + BO_PING);
  float* pong          = (float*)(ws + BO_PONG);
  __hip_bfloat16* wts  = (__hip_bfloat16*)(ws + BO_W);
  __hip_bfloat16* t1   = (__hip_bfloat16*)(ws + BO_T1);
  __hip_bfloat16* g1   = (__hip_bfloat16*)(ws + BO_G1);

  float* out      = (float*)d_out;
  float* out_enh  = out;                 // [4][24][128][128]
  float* out_cg   = out + 1572864;       // [4][6][128][128]
  float* out_cond = out + 1966080;       // [4][1][128][128]

  prep_kernel<<<512, 256, 0, stream>>>(w_te1, w_te2, w_g1, w_f1, w_f2, w_g2, emb, labels, wsf);
  conv3x3_kernel<float, 3,  false, false><<<dim3(64, 2, 4), 256, 0, stream>>>(texf, wsf + O_WTE1, b_te1, nullptr, t1, 64);
  conv3x3_kernel<__hip_bfloat16, 64, false, false><<<dim3(64, 4, 4), 256, 0, stream>>>(t1,   wsf + O_WTE2, b_te2, nullptr, tex, 128);
  conv3x3_kernel<__hip_bfloat16, 128,false, false><<<dim3(64, 2, 4), 256, 0, stream>>>(tex,  wsf + O_WG1,  b_g1,  nullptr, g1, 64);
  gate2_kernel<<<dim3(64, 4), 256, 0, stream>>>(g1, wsf + O_WG2, b_g2, labels, ci, out_cg, out_cond, wsf + O_INT);
  conv3x3_kernel<__hip_bfloat16, 128,true,  true ><<<dim3(64, 8, 4), 256, 0, stream>>>(tex,  wsf + O_WF1,  b_f1,  wsf + O_S, f1, 256);
  conv1x1_softmax_kernel<<<dim3(64, 2, 4), 256, 0, stream>>>(f1, wsf + O_WF2, b_f2, wsf + O_INT, wts);

  dim3 dgrid(2, 32, 96), dblk(64, 4, 1);
  diff_kernel<<<dgrid, dblk, 0, stream>>>(depth, wts, ping);
  diff_kernel<<<dgrid, dblk, 0, stream>>>(ping, wts, pong);
  diff_kernel<<<dgrid, dblk, 0, stream>>>(pong, wts, ping);
  diff_kernel<<<dgrid, dblk, 0, stream>>>(ping, wts, pong);
  diff_kernel<<<dgrid, dblk, 0, stream>>>(pong, wts, ping);
  diff_kernel<<<dgrid, dblk, 0, stream>>>(ping, wts, pong);
  diff_kernel<<<dgrid, dblk, 0, stream>>>(pong, wts, ping);
  diff_kernel<<<dgrid, dblk, 0, stream>>>(ping, wts, out_enh);
}

// Round 4
// 3000.761 us; speedup vs baseline: 1.2013x; 1.2013x over previous
//
#include <hip/hip_runtime.h>
#include <hip/hip_bf16.h>
#include <stdint.h>

#define DINL __device__ __forceinline__

DINL float bf2f(__hip_bfloat16 v) { return __bfloat162float(v); }
DINL __hip_bfloat16 f2bf(float v) { return __float2bfloat16(v); }
DINL float bflo(unsigned int u) { return __uint_as_float(u << 16); }
DINL float bfhi(unsigned int u) { return __uint_as_float(u & 0xffff0000u); }

DINL float loadf(float v) { return v; }
DINL float loadf(__hip_bfloat16 v) { return __bfloat162float(v); }

// ---------------- ws layout ----------------
// fp32 region (float offsets):
#define O_WTE1 0         // [2][3][9][32]      1728
#define O_WTE2 2048      // [4][64][9][32]     73728
#define O_WG1  75776     // [2][128][9][32]    73728
#define O_WF1  149504    // [8][128][9][32]    294912
#define O_WF2  444416    // [1176][256]        301056
#define O_WG2  745472    // [6][64]            384
#define O_S    745984    // [4][8][9][32]      9216
#define O_INT  755200    // [4][16384]         65536
// byte offsets:
#define BO_TEX  4194304u    // tex bf16 [4][128][128][128]  16.78 MB
#define BO_F1   20971520u   // f1 bf16 pixel-major [4][16384][256]  33.55 MB
#define BO_PING 54525952u   // fp32 [4*24*16384]  6.29 MB
#define BO_PONG 60817408u
#define BO_W    67108864u   // weights bf16 [4][24][49][16384]  154.14 MB
#define BO_T1   BO_W            // t1 bf16 (dead before W written)
#define BO_G1   (BO_W + 16777216u)  // g1 bf16 (dead before W written)

// ---------------- prep: re-layout weights (block layout) + S table ----------------
__global__ __launch_bounds__(256) void prep_kernel(
    const float* __restrict__ w_te1, const float* __restrict__ w_te2,
    const float* __restrict__ w_g1,  const float* __restrict__ w_f1,
    const float* __restrict__ w_f2,  const float* __restrict__ w_g2,
    const float* __restrict__ emb,   const int* __restrict__ labels,
    float* __restrict__ wsf)
{
  const int gid = blockIdx.x * 256 + threadIdx.x;
  const int stride = gridDim.x * 256;
  const int N1 = 1728, N2 = N1 + 73728, N3 = N2 + 73728, N4 = N3 + 294912,
            N5 = N4 + 301056, N6 = N5 + 384;
  for (int i = gid; i < N6; i += stride) {
    if (i < N1) {
      int s = i; int o = s / 27; int r = s - o * 27; int ic = r / 9; int t = r - ic * 9;
      wsf[O_WTE1 + (((o >> 5) * 3 + ic) * 9 + t) * 32 + (o & 31)] = w_te1[s];
    } else if (i < N2) {
      int s = i - N1; int o = s / 576; int r = s - o * 576; int ic = r / 9; int t = r - ic * 9;
      wsf[O_WTE2 + (((o >> 5) * 64 + ic) * 9 + t) * 32 + (o & 31)] = w_te2[s];
    } else if (i < N3) {
      int s = i - N2; int o = s / 1152; int r = s - o * 1152; int ic = r / 9; int t = r - ic * 9;
      wsf[O_WG1 + (((o >> 5) * 128 + ic) * 9 + t) * 32 + (o & 31)] = w_g1[s];
    } else if (i < N4) {
      int s = i - N3; int o = s / 1152; int r = s - o * 1152; int ic = r / 9; int t = r - ic * 9;
      wsf[O_WF1 + (((o >> 5) * 128 + ic) * 9 + t) * 32 + (o & 31)] = w_f1[o * 2304 + r];
    } else if (i < N5) {
      int s = i - N4;
      wsf[O_WF2 + s] = w_f2[s];
    } else {
      int s = i - N5;
      wsf[O_WG2 + s] = w_g2[s];
    }
  }
  // S[b][o][t] = sum_i w_f1[o][128+i][t] * emb[label_b][i]   (emb half of fusion conv1)
  if (gid < 9216) {
    int b = gid / 2304; int r = gid - b * 2304; int o = r / 9; int t = r - o * 9;
    int lab = labels[b];
    float sum = 0.f;
    for (int i = 0; i < 128; ++i)
      sum += w_f1[o * 2304 + (128 + i) * 9 + t] * emb[lab * 128 + i];
    wsf[O_S + b * 2304 + (o >> 5) * 288 + t * 32 + (o & 31)] = sum;
  }
}

// ---------------- generic 3x3 conv (zero pad), fp32 acc, ReLU ----------------
// weights fp32 layout [och/32][ICH][9][32]; 16x16 pixel tile; 32 och per block.
// __launch_bounds__(256,2): VGPR cap 256 — acc[32]+staging needs ~80; without the
// explicit waves-per-EU floor the allocator spilled (R3: VGPR_Count=24, 31ms dispatch).
template<typename TIn, int ICH, bool ADD_S, bool PIXMAJOR>
__global__ __launch_bounds__(256, 2) void conv3x3_kernel(
    const TIn* __restrict__ in, const float* __restrict__ wf,
    const float* __restrict__ bias, const float* __restrict__ S,
    __hip_bfloat16* __restrict__ out, const int och_total)
{
  constexpr int CH = (ICH < 16) ? ICH : 16;
  constexpr int NCHUNK = ICH / CH;
  __shared__ TIn sIn[CH][18][20];
  const int tid = threadIdx.x;
  const int b = blockIdx.z;
  const int ob = blockIdx.y;
  const int och0 = ob * 32;
  const int tileY = blockIdx.x >> 3, tileX = blockIdx.x & 7;
  const int ty = tid >> 4, tx = tid & 15;
  const int h = tileY * 16 + ty, w = tileX * 16 + tx;
  const int h0 = tileY * 16 - 1, w0 = tileX * 16 - 1;

  float acc[32];
#pragma unroll
  for (int o = 0; o < 32; ++o) acc[o] = bias[och0 + o];

  for (int cc = 0; cc < NCHUNK; ++cc) {
    if (cc) __syncthreads();
    for (int e = tid; e < CH * 324; e += 256) {
      int ic = e / 324, r = e - ic * 324;
      int y = r / 18, x = r - y * 18;
      int gh = h0 + y, gw = w0 + x;
      TIn v = TIn(0.f);
      if ((unsigned)gh < 128u && (unsigned)gw < 128u)
        v = in[((b * ICH + cc * CH + ic) << 14) + (gh << 7) + gw];
      sIn[ic][y][x] = v;
    }
    __syncthreads();
#pragma unroll 1
    for (int ic = 0; ic < CH; ++ic) {
      const float* wrow = wf + (ob * ICH + cc * CH + ic) * 288;  // [9][32]
#pragma unroll
      for (int t = 0; t < 9; ++t) {
        const int kh = t / 3, kw = t - kh * 3;
        const float v = loadf(sIn[ic][ty + kh][tx + kw]);
#pragma unroll
        for (int o = 0; o < 32; ++o)
          acc[o] = fmaf(wrow[t * 32 + o], v, acc[o]);
      }
    }
  }

  if constexpr (ADD_S) {
    // spatially-constant emb contribution, masked by zero-pad tap validity
    const float* Sp = S + b * 2304 + ob * 288;
#pragma unroll
    for (int t = 0; t < 9; ++t) {
      const int kh = t / 3, kw = t - kh * 3;
      const bool vh = (kh == 1) ? true : (kh == 0 ? (h > 0) : (h < 127));
      const bool vw = (kw == 1) ? true : (kw == 0 ? (w > 0) : (w < 127));
      const float msk = (vh && vw) ? 1.f : 0.f;
#pragma unroll
      for (int o = 0; o < 32; ++o)
        acc[o] = fmaf(msk, Sp[t * 32 + o], acc[o]);
    }
  }

  const int pix = (h << 7) + w;
  if constexpr (!PIXMAJOR) {
#pragma unroll
    for (int o = 0; o < 32; ++o)
      out[((b * och_total + och0 + o) << 14) + pix] = f2bf(fmaxf(acc[o], 0.f));
  } else {
    union { uint4 u4[4]; __hip_bfloat16 hh[32]; } pk;
#pragma unroll
    for (int o = 0; o < 32; ++o) pk.hh[o] = f2bf(fmaxf(acc[o], 0.f));
    uint4* dst = reinterpret_cast<uint4*>(out + ((size_t)(b << 14) + pix) * och_total + och0);
#pragma unroll
    for (int i = 0; i < 4; ++i) dst[i] = pk.u4[i];
  }
}

// ---------------- gate 1x1 conv + sigmoid + class_gate / intensity / condition_map ----------------
__global__ __launch_bounds__(256) void gate2_kernel(
    const __hip_bfloat16* __restrict__ g1, const float* __restrict__ wg2,
    const float* __restrict__ b_g2, const int* __restrict__ labels,
    const float* __restrict__ ci,
    float* __restrict__ out_cg, float* __restrict__ out_cond,
    float* __restrict__ inten)
{
  const int b = blockIdx.y;
  const int pix = blockIdx.x * 256 + threadIdx.x;
  float acc[6];
#pragma unroll
  for (int k = 0; k < 6; ++k) acc[k] = b_g2[k];
  for (int i = 0; i < 64; ++i) {
    float v = bf2f(g1[((b * 64 + i) << 14) + pix]);
#pragma unroll
    for (int k = 0; k < 6; ++k) acc[k] = fmaf(wg2[k * 64 + i], v, acc[k]);
  }
  const int lab = labels[b];
  float gate[6], gl = 0.f;
#pragma unroll
  for (int k = 0; k < 6; ++k) {
    gate[k] = 1.f / (1.f + __expf(-acc[k]));
    gl = (k == lab) ? gate[k] : gl;
  }
  const float civ = ci[lab];
  const float it = gl * civ;
#pragma unroll
  for (int k = 0; k < 6; ++k)
    out_cg[((b * 6 + k) << 14) + pix] = (k == lab) ? gate[k] : 0.f;
  inten[(b << 14) + pix] = it;
  out_cond[(b << 14) + pix] = it * gl;
}

// ---------------- fusion 1x1 conv (256->1176) + intensity scale + softmax(49) -> bf16 weights ----------------
// __launch_bounds__(256,2): acc[49]+addr needs ~90 VGPR; R3's default heuristic gave
// VGPR_Count=40 (spill). 4 channel-groups -> 1024 blocks (16 waves/CU grid occupancy).
__global__ __launch_bounds__(256, 2) void conv1x1_softmax_kernel(
    const __hip_bfloat16* __restrict__ f1, const float* __restrict__ wf2,
    const float* __restrict__ b_f2, const float* __restrict__ inten,
    __hip_bfloat16* __restrict__ wout)
{
  const int b = blockIdx.z;
  const int c0 = blockIdx.y * 6;
  const int pix = blockIdx.x * 256 + threadIdx.x;
  const float s = inten[(b << 14) + pix];
  const uint4* fin = reinterpret_cast<const uint4*>(f1) + (((size_t)(b << 14) + pix) << 5);
  for (int cl = 0; cl < 6; ++cl) {
    const int c = c0 + cl;
    const float* wp = wf2 + (size_t)c * 49 * 256;
    float acc[49];
#pragma unroll
    for (int t = 0; t < 49; ++t) acc[t] = b_f2[c * 49 + t];
#pragma unroll 1
    for (int i4 = 0; i4 < 32; ++i4) {
      const uint4 q = fin[i4];
      const float v0 = bflo(q.x), v1 = bfhi(q.x), v2 = bflo(q.y), v3 = bfhi(q.y);
      const float v4 = bflo(q.z), v5 = bfhi(q.z), v6 = bflo(q.w), v7 = bfhi(q.w);
      const float* wq = wp + i4 * 8;
#pragma unroll
      for (int t = 0; t < 49; ++t) {
        const float* w8 = wq + t * 256;
        acc[t] = fmaf(w8[0], v0, acc[t]); acc[t] = fmaf(w8[1], v1, acc[t]);
        acc[t] = fmaf(w8[2], v2, acc[t]); acc[t] = fmaf(w8[3], v3, acc[t]);
        acc[t] = fmaf(w8[4], v4, acc[t]); acc[t] = fmaf(w8[5], v5, acc[t]);
        acc[t] = fmaf(w8[6], v6, acc[t]); acc[t] = fmaf(w8[7], v7, acc[t]);
      }
    }
    float m = -3.4e38f;
#pragma unroll
    for (int t = 0; t < 49; ++t) { acc[t] *= s; m = fmaxf(m, acc[t]); }
    float sum = 0.f;
#pragma unroll
    for (int t = 0; t < 49; ++t) { acc[t] = __expf(acc[t] - m); sum += acc[t]; }
    const float r = 1.f / sum;
    __hip_bfloat16* wo = wout + (((size_t)(b * 24 + c) * 49) << 14) + pix;
#pragma unroll
    for (int t = 0; t < 49; ++t) wo[(size_t)t << 14] = f2bf(acc[t] * r);
  }
}

// ---------------- one diffusion step: per-pixel 7x7 weighted average, edge-clamped ----------------
__global__ __launch_bounds__(256) void diff_kernel(
    const float* __restrict__ lin, const __hip_bfloat16* __restrict__ wts,
    float* __restrict__ lout)
{
  __shared__ float sT[10][70];   // 4+6 rows, 64+6 cols
  const int bc = blockIdx.z;
  const int w0 = blockIdx.x * 64, h0 = blockIdx.y * 4;
  const int tid = threadIdx.y * 64 + threadIdx.x;
  for (int e = tid; e < 700; e += 256) {
    int y = e / 70, x = e - y * 70;
    int gh = min(max(h0 - 3 + y, 0), 127), gw = min(max(w0 - 3 + x, 0), 127);
    sT[y][x] = lin[(bc << 14) + (gh << 7) + gw];
  }
  __syncthreads();
  const int tx = threadIdx.x, ty = threadIdx.y;
  const int pix = ((h0 + ty) << 7) + w0 + tx;
  const __hip_bfloat16* wp = wts + (((size_t)bc * 49) << 14) + pix;
  float acc = 0.f;
#pragma unroll
  for (int t = 0; t < 49; ++t) {
    const int kh = t / 7, kw = t - kh * 7;
    acc = fmaf(bf2f(wp[(size_t)t << 14]), sT[ty + kh][tx + kw], acc);
  }
  lout[(bc << 14) + pix] = acc;
}

// ---------------- orchestration ----------------
extern "C" void kernel_launch(void* const* d_in, const int* in_sizes, int n_in,
                              void* d_out, int out_size, void* d_ws, size_t ws_size,
                              hipStream_t stream)
{
  const float* depth = (const float*)d_in[0];
  const float* texf  = (const float*)d_in[1];
  const int*   labels= (const int*)d_in[2];
  const float* w_te1 = (const float*)d_in[3];
  const float* b_te1 = (const float*)d_in[4];
  const float* w_te2 = (const float*)d_in[5];
  const float* b_te2 = (const float*)d_in[6];
  const float* emb   = (const float*)d_in[7];
  const float* w_f1  = (const float*)d_in[8];
  const float* b_f1  = (const float*)d_in[9];
  const float* w_f2  = (const float*)d_in[10];
  const float* b_f2  = (const float*)d_in[11];
  const float* w_g1  = (const float*)d_in[12];
  const float* b_g1  = (const float*)d_in[13];
  const float* w_g2  = (const float*)d_in[14];
  const float* b_g2  = (const float*)d_in[15];
  const float* ci    = (const float*)d_in[16];

  char*  ws  = (char*)d_ws;
  float* wsf = (float*)d_ws;
  __hip_bfloat16* tex  = (__hip_bfloat16*)(ws + BO_TEX);
  __hip_bfloat16* f1   = (__hip_bfloat16*)(ws + BO_F1);
  float* ping          = (float*)(ws + BO_PING);
  float* pong          = (float*)(ws + BO_PONG);
  __hip_bfloat16* wts  = (__hip_bfloat16*)(ws + BO_W);
  __hip_bfloat16* t1   = (__hip_bfloat16*)(ws + BO_T1);
  __hip_bfloat16* g1   = (__hip_bfloat16*)(ws + BO_G1);

  float* out      = (float*)d_out;
  float* out_enh  = out;                 // [4][24][128][128]
  float* out_cg   = out + 1572864;       // [4][6][128][128]
  float* out_cond = out + 1966080;       // [4][1][128][128]

  prep_kernel<<<512, 256, 0, stream>>>(w_te1, w_te2, w_g1, w_f1, w_f2, w_g2, emb, labels, wsf);
  conv3x3_kernel<float, 3,  false, false><<<dim3(64, 2, 4), 256, 0, stream>>>(texf, wsf + O_WTE1, b_te1, nullptr, t1, 64);
  conv3x3_kernel<__hip_bfloat16, 64, false, false><<<dim3(64, 4, 4), 256, 0, stream>>>(t1,   wsf + O_WTE2, b_te2, nullptr, tex, 128);
  conv3x3_kernel<__hip_bfloat16, 128,false, false><<<dim3(64, 2, 4), 256, 0, stream>>>(tex,  wsf + O_WG1,  b_g1,  nullptr, g1, 64);
  gate2_kernel<<<dim3(64, 4), 256, 0, stream>>>(g1, wsf + O_WG2, b_g2, labels, ci, out_cg, out_cond, wsf + O_INT);
  conv3x3_kernel<__hip_bfloat16, 128,true,  true ><<<dim3(64, 8, 4), 256, 0, stream>>>(tex,  wsf + O_WF1,  b_f1,  wsf + O_S, f1, 256);
  conv1x1_softmax_kernel<<<dim3(64, 4, 4), 256, 0, stream>>>(f1, wsf + O_WF2, b_f2, wsf + O_INT, wts);

  dim3 dgrid(2, 32, 96), dblk(64, 4, 1);
  diff_kernel<<<dgrid, dblk, 0, stream>>>(depth, wts, ping);
  diff_kernel<<<dgrid, dblk, 0, stream>>>(ping, wts, pong);
  diff_kernel<<<dgrid, dblk, 0, stream>>>(pong, wts, ping);
  diff_kernel<<<dgrid, dblk, 0, stream>>>(ping, wts, pong);
  diff_kernel<<<dgrid, dblk, 0, stream>>>(pong, wts, ping);
  diff_kernel<<<dgrid, dblk, 0, stream>>>(ping, wts, pong);
  diff_kernel<<<dgrid, dblk, 0, stream>>>(pong, wts, ping);
  diff_kernel<<<dgrid, dblk, 0, stream>>>(ping, wts, out_enh);
}

// Round 5
// 1607.827 us; speedup vs baseline: 2.2421x; 1.8663x over previous
//
#include <hip/hip_runtime.h>
#include <hip/hip_bf16.h>
#include <stdint.h>

#define DINL __device__ __forceinline__

DINL float bf2f(__hip_bfloat16 v) { return __bfloat162float(v); }
DINL __hip_bfloat16 f2bf(float v) { return __float2bfloat16(v); }

DINL float loadf(float v) { return v; }
DINL float loadf(__hip_bfloat16 v) { return __bfloat162float(v); }

typedef __attribute__((ext_vector_type(8))) short bf16x8;
typedef __attribute__((ext_vector_type(4))) float f32x4;

// ---------------- ws layout ----------------
// fp32 region (float offsets):
#define O_WTE1 0         // [2][3][9][32]      1728
#define O_WTE2 2048      // [4][64][9][32]     73728
#define O_WG1  75776     // [2][128][9][32]    73728
#define O_WF1  149504    // [8][128][9][32]    294912
#define O_WG2  745472    // [6][64]            384
#define O_S    745984    // [4][8][9][32]      9216
#define O_INT  755200    // [4][16384]         65536  (ends at float 820736 = byte 3282944)
// byte offsets:
#define BO_W2B  3282944u    // w_f2 bf16 padded [24][64][256]  786432 B (ends 4069376 <= BO_TEX)
#define BO_TEX  4194304u    // tex bf16 [4][128][128][128]  16.78 MB
#define BO_F1   20971520u   // f1 bf16 pixel-major [4][16384][256]  33.55 MB
#define BO_PING 54525952u   // fp32 [4*24*16384]  6.29 MB
#define BO_PONG 60817408u
#define BO_W    67108864u   // weights bf16 [4][24][49][16384]  154.14 MB
#define BO_T1   BO_W            // t1 bf16 (dead before W written)
#define BO_G1   (BO_W + 16777216u)  // g1 bf16 (dead before W written)

// ---------------- prep: re-layout weights (block layout) + S table + W2 bf16 pack ----------------
__global__ __launch_bounds__(256) void prep_kernel(
    const float* __restrict__ w_te1, const float* __restrict__ w_te2,
    const float* __restrict__ w_g1,  const float* __restrict__ w_f1,
    const float* __restrict__ w_f2,  const float* __restrict__ w_g2,
    const float* __restrict__ emb,   const int* __restrict__ labels,
    float* __restrict__ wsf)
{
  const int gid = blockIdx.x * 256 + threadIdx.x;
  const int stride = gridDim.x * 256;
  const int N1 = 1728, N2 = N1 + 73728, N3 = N2 + 73728, N4 = N3 + 294912,
            N5 = N4 + 393216, N6 = N5 + 384;
  __hip_bfloat16* w2b = (__hip_bfloat16*)((char*)wsf + BO_W2B);
  for (int i = gid; i < N6; i += stride) {
    if (i < N1) {
      int s = i; int o = s / 27; int r = s - o * 27; int ic = r / 9; int t = r - ic * 9;
      wsf[O_WTE1 + (((o >> 5) * 3 + ic) * 9 + t) * 32 + (o & 31)] = w_te1[s];
    } else if (i < N2) {
      int s = i - N1; int o = s / 576; int r = s - o * 576; int ic = r / 9; int t = r - ic * 9;
      wsf[O_WTE2 + (((o >> 5) * 64 + ic) * 9 + t) * 32 + (o & 31)] = w_te2[s];
    } else if (i < N3) {
      int s = i - N2; int o = s / 1152; int r = s - o * 1152; int ic = r / 9; int t = r - ic * 9;
      wsf[O_WG1 + (((o >> 5) * 128 + ic) * 9 + t) * 32 + (o & 31)] = w_g1[s];
    } else if (i < N4) {
      int s = i - N3; int o = s / 1152; int r = s - o * 1152; int ic = r / 9; int t = r - ic * 9;
      wsf[O_WF1 + (((o >> 5) * 128 + ic) * 9 + t) * 32 + (o & 31)] = w_f1[o * 2304 + r];
    } else if (i < N5) {
      // pack w_f2 [1176][256] fp32 -> bf16 [24][64][256], taps 49..63 zeroed
      int s = i - N4;
      int k = s & 255; int t = (s >> 8) & 63; int c = s >> 14;
      float v = (t < 49) ? w_f2[(c * 49 + t) * 256 + k] : 0.f;
      w2b[s] = f2bf(v);
    } else {
      int s = i - N5;
      wsf[O_WG2 + s] = w_g2[s];
    }
  }
  // S[b][o][t] = sum_i w_f1[o][128+i][t] * emb[label_b][i]   (emb half of fusion conv1)
  if (gid < 9216) {
    int b = gid / 2304; int r = gid - b * 2304; int o = r / 9; int t = r - o * 9;
    int lab = labels[b];
    float sum = 0.f;
    for (int i = 0; i < 128; ++i)
      sum += w_f1[o * 2304 + (128 + i) * 9 + t] * emb[lab * 128 + i];
    wsf[O_S + b * 2304 + (o >> 5) * 288 + t * 32 + (o & 31)] = sum;
  }
}

// ---------------- generic 3x3 conv (zero pad), fp32 acc, ReLU ----------------
// weights fp32 layout [och/32][ICH][9][32]; 16x16 pixel tile; 32 och per block.
template<typename TIn, int ICH, bool ADD_S, bool PIXMAJOR>
__global__ __launch_bounds__(256, 2) void conv3x3_kernel(
    const TIn* __restrict__ in, const float* __restrict__ wf,
    const float* __restrict__ bias, const float* __restrict__ S,
    __hip_bfloat16* __restrict__ out, const int och_total)
{
  constexpr int CH = (ICH < 16) ? ICH : 16;
  constexpr int NCHUNK = ICH / CH;
  __shared__ TIn sIn[CH][18][20];
  const int tid = threadIdx.x;
  const int b = blockIdx.z;
  const int ob = blockIdx.y;
  const int och0 = ob * 32;
  const int tileY = blockIdx.x >> 3, tileX = blockIdx.x & 7;
  const int ty = tid >> 4, tx = tid & 15;
  const int h = tileY * 16 + ty, w = tileX * 16 + tx;
  const int h0 = tileY * 16 - 1, w0 = tileX * 16 - 1;

  float acc[32];
#pragma unroll
  for (int o = 0; o < 32; ++o) acc[o] = bias[och0 + o];

  for (int cc = 0; cc < NCHUNK; ++cc) {
    if (cc) __syncthreads();
    for (int e = tid; e < CH * 324; e += 256) {
      int ic = e / 324, r = e - ic * 324;
      int y = r / 18, x = r - y * 18;
      int gh = h0 + y, gw = w0 + x;
      TIn v = TIn(0.f);
      if ((unsigned)gh < 128u && (unsigned)gw < 128u)
        v = in[((b * ICH + cc * CH + ic) << 14) + (gh << 7) + gw];
      sIn[ic][y][x] = v;
    }
    __syncthreads();
#pragma unroll 1
    for (int ic = 0; ic < CH; ++ic) {
      const float* wrow = wf + (ob * ICH + cc * CH + ic) * 288;  // [9][32]
#pragma unroll
      for (int t = 0; t < 9; ++t) {
        const int kh = t / 3, kw = t - kh * 3;
        const float v = loadf(sIn[ic][ty + kh][tx + kw]);
#pragma unroll
        for (int o = 0; o < 32; ++o)
          acc[o] = fmaf(wrow[t * 32 + o], v, acc[o]);
      }
    }
  }

  if constexpr (ADD_S) {
    // spatially-constant emb contribution, masked by zero-pad tap validity
    const float* Sp = S + b * 2304 + ob * 288;
#pragma unroll
    for (int t = 0; t < 9; ++t) {
      const int kh = t / 3, kw = t - kh * 3;
      const bool vh = (kh == 1) ? true : (kh == 0 ? (h > 0) : (h < 127));
      const bool vw = (kw == 1) ? true : (kw == 0 ? (w > 0) : (w < 127));
      const float msk = (vh && vw) ? 1.f : 0.f;
#pragma unroll
      for (int o = 0; o < 32; ++o)
        acc[o] = fmaf(msk, Sp[t * 32 + o], acc[o]);
    }
  }

  const int pix = (h << 7) + w;
  if constexpr (!PIXMAJOR) {
#pragma unroll
    for (int o = 0; o < 32; ++o)
      out[((b * och_total + och0 + o) << 14) + pix] = f2bf(fmaxf(acc[o], 0.f));
  } else {
    union { uint4 u4[4]; __hip_bfloat16 hh[32]; } pk;
#pragma unroll
    for (int o = 0; o < 32; ++o) pk.hh[o] = f2bf(fmaxf(acc[o], 0.f));
    uint4* dst = reinterpret_cast<uint4*>(out + ((size_t)(b << 14) + pix) * och_total + och0);
#pragma unroll
    for (int i = 0; i < 4; ++i) dst[i] = pk.u4[i];
  }
}

// ---------------- gate 1x1 conv + sigmoid + class_gate / intensity / condition_map ----------------
__global__ __launch_bounds__(256) void gate2_kernel(
    const __hip_bfloat16* __restrict__ g1, const float* __restrict__ wg2,
    const float* __restrict__ b_g2, const int* __restrict__ labels,
    const float* __restrict__ ci,
    float* __restrict__ out_cg, float* __restrict__ out_cond,
    float* __restrict__ inten)
{
  const int b = blockIdx.y;
  const int pix = blockIdx.x * 256 + threadIdx.x;
  float acc[6];
#pragma unroll
  for (int k = 0; k < 6; ++k) acc[k] = b_g2[k];
  for (int i = 0; i < 64; ++i) {
    float v = bf2f(g1[((b * 64 + i) << 14) + pix]);
#pragma unroll
    for (int k = 0; k < 6; ++k) acc[k] = fmaf(wg2[k * 64 + i], v, acc[k]);
  }
  const int lab = labels[b];
  float gate[6], gl = 0.f;
#pragma unroll
  for (int k = 0; k < 6; ++k) {
    gate[k] = 1.f / (1.f + __expf(-acc[k]));
    gl = (k == lab) ? gate[k] : gl;
  }
  const float civ = ci[lab];
  const float it = gl * civ;
#pragma unroll
  for (int k = 0; k < 6; ++k)
    out_cg[((b * 6 + k) << 14) + pix] = (k == lab) ? gate[k] : 0.f;
  inten[(b << 14) + pix] = it;
  out_cond[(b << 14) + pix] = it * gl;
}

// ---------------- fused MFMA GEMM (65536x1176x256) + intensity + softmax(49) ----------------
// W2 padded per-channel to 64 taps so one 64-wide N-tile == one channel.
// Block: 64 pixels x 1 channel; full K=256 in LDS; 4 waves x 4 m-tiles x 8 k-steps
// of mfma_f32_16x16x32_bf16. Logits go C-frag -> LDS -> per-pixel softmax (no
// register arrays: R3/R4 showed the allocator scratch-spills float[49]).
__global__ __launch_bounds__(256, 2) void gemm_softmax_kernel(
    const __hip_bfloat16* __restrict__ f1, const __hip_bfloat16* __restrict__ w2b,
    const float* __restrict__ b_f2, const float* __restrict__ inten,
    __hip_bfloat16* __restrict__ wout)
{
  __shared__ __hip_bfloat16 sA[64][264];   // 64 pixels x 256 K (+8 pad: frag reads 2-way max)
  __shared__ __hip_bfloat16 sB[64][264];   // 64 taps   x 256 K
  const int c = blockIdx.x;       // channel 0..23 (fastest-varying: f1 tile L2 reuse)
  const int pix0 = blockIdx.y * 64;
  const int tid = threadIdx.x;

  {
    const uint4* srcA = (const uint4*)(f1 + (size_t)pix0 * 256);
    const uint4* srcB = (const uint4*)(w2b + (size_t)c * 64 * 256);
    for (int i = tid; i < 2048; i += 256) {
      int r = i >> 5, q = i & 31;
      *(uint4*)&sA[r][q * 8] = srcA[i];
      *(uint4*)&sB[r][q * 8] = srcB[i];
    }
  }
  __syncthreads();

  const int wave = tid >> 6, lane = tid & 63;
  const int m = lane & 15, quad = lane >> 4;
  f32x4 acc[4] = {f32x4{0,0,0,0}, f32x4{0,0,0,0}, f32x4{0,0,0,0}, f32x4{0,0,0,0}};
#pragma unroll
  for (int ks = 0; ks < 8; ++ks) {
    const int ko = ks * 32 + quad * 8;
    const bf16x8 bfr = *(const bf16x8*)&sB[wave * 16 + m][ko];
#pragma unroll
    for (int mt = 0; mt < 4; ++mt) {
      const bf16x8 afr = *(const bf16x8*)&sA[mt * 16 + m][ko];
      acc[mt] = __builtin_amdgcn_mfma_f32_16x16x32_bf16(afr, bfr, acc[mt], 0, 0, 0);
    }
  }
  __syncthreads();

  // logits -> LDS (alias sB): [64 t][66 pix] fp32.  C/D map: col(t)=lane&15, row(pix)=quad*4+r
  float* sL = (float*)&sB[0][0];
#pragma unroll
  for (int mt = 0; mt < 4; ++mt)
#pragma unroll
    for (int r = 0; r < 4; ++r)
      sL[(wave * 16 + m) * 66 + (mt * 16 + quad * 4 + r)] = acc[mt][r];
  __syncthreads();

  if (tid < 64) {
    const int P = pix0 + tid;
    const float s = inten[P];
    // pass 1: bias + scale, find max (in place in LDS; each thread owns its column)
    float mx = -3.4e38f;
    for (int t = 0; t < 49; ++t) {
      float v = (sL[t * 66 + tid] + b_f2[c * 49 + t]) * s;
      sL[t * 66 + tid] = v;
      mx = fmaxf(mx, v);
    }
    // pass 2: exp + sum
    float sum = 0.f;
    for (int t = 0; t < 49; ++t) {
      float e = __expf(sL[t * 66 + tid] - mx);
      sL[t * 66 + tid] = e;
      sum += e;
    }
    const float rs = 1.f / sum;
    const int b = P >> 14, p = P & 16383;
    __hip_bfloat16* wo = wout + (((size_t)(b * 24 + c) * 49) << 14) + p;
    for (int t = 0; t < 49; ++t)
      wo[(size_t)t << 14] = f2bf(sL[t * 66 + tid] * rs);
  }
}

// ---------------- one diffusion step: per-pixel 7x7 weighted average, edge-clamped ----------------
__global__ __launch_bounds__(256) void diff_kernel(
    const float* __restrict__ lin, const __hip_bfloat16* __restrict__ wts,
    float* __restrict__ lout)
{
  __shared__ float sT[10][70];   // 4+6 rows, 64+6 cols
  const int bc = blockIdx.z;
  const int w0 = blockIdx.x * 64, h0 = blockIdx.y * 4;
  const int tid = threadIdx.y * 64 + threadIdx.x;
  for (int e = tid; e < 700; e += 256) {
    int y = e / 70, x = e - y * 70;
    int gh = min(max(h0 - 3 + y, 0), 127), gw = min(max(w0 - 3 + x, 0), 127);
    sT[y][x] = lin[(bc << 14) + (gh << 7) + gw];
  }
  __syncthreads();
  const int tx = threadIdx.x, ty = threadIdx.y;
  const int pix = ((h0 + ty) << 7) + w0 + tx;
  const __hip_bfloat16* wp = wts + (((size_t)bc * 49) << 14) + pix;
  float acc = 0.f;
#pragma unroll
  for (int t = 0; t < 49; ++t) {
    const int kh = t / 7, kw = t - kh * 7;
    acc = fmaf(bf2f(wp[(size_t)t << 14]), sT[ty + kh][tx + kw], acc);
  }
  lout[(bc << 14) + pix] = acc;
}

// ---------------- orchestration ----------------
extern "C" void kernel_launch(void* const* d_in, const int* in_sizes, int n_in,
                              void* d_out, int out_size, void* d_ws, size_t ws_size,
                              hipStream_t stream)
{
  const float* depth = (const float*)d_in[0];
  const float* texf  = (const float*)d_in[1];
  const int*   labels= (const int*)d_in[2];
  const float* w_te1 = (const float*)d_in[3];
  const float* b_te1 = (const float*)d_in[4];
  const float* w_te2 = (const float*)d_in[5];
  const float* b_te2 = (const float*)d_in[6];
  const float* emb   = (const float*)d_in[7];
  const float* w_f1  = (const float*)d_in[8];
  const float* b_f1  = (const float*)d_in[9];
  const float* w_f2  = (const float*)d_in[10];
  const float* b_f2  = (const float*)d_in[11];
  const float* w_g1  = (const float*)d_in[12];
  const float* b_g1  = (const float*)d_in[13];
  const float* w_g2  = (const float*)d_in[14];
  const float* b_g2  = (const float*)d_in[15];
  const float* ci    = (const float*)d_in[16];

  char*  ws  = (char*)d_ws;
  float* wsf = (float*)d_ws;
  __hip_bfloat16* w2bf = (__hip_bfloat16*)(ws + BO_W2B);
  __hip_bfloat16* tex  = (__hip_bfloat16*)(ws + BO_TEX);
  __hip_bfloat16* f1   = (__hip_bfloat16*)(ws + BO_F1);
  float* ping          = (float*)(ws + BO_PING);
  float* pong          = (float*)(ws + BO_PONG);
  __hip_bfloat16* wts  = (__hip_bfloat16*)(ws + BO_W);
  __hip_bfloat16* t1   = (__hip_bfloat16*)(ws + BO_T1);
  __hip_bfloat16* g1   = (__hip_bfloat16*)(ws + BO_G1);

  float* out      = (float*)d_out;
  float* out_enh  = out;                 // [4][24][128][128]
  float* out_cg   = out + 1572864;       // [4][6][128][128]
  float* out_cond = out + 1966080;       // [4][1][128][128]

  prep_kernel<<<512, 256, 0, stream>>>(w_te1, w_te2, w_g1, w_f1, w_f2, w_g2, emb, labels, wsf);
  conv3x3_kernel<float, 3,  false, false><<<dim3(64, 2, 4), 256, 0, stream>>>(texf, wsf + O_WTE1, b_te1, nullptr, t1, 64);
  conv3x3_kernel<__hip_bfloat16, 64, false, false><<<dim3(64, 4, 4), 256, 0, stream>>>(t1,   wsf + O_WTE2, b_te2, nullptr, tex, 128);
  conv3x3_kernel<__hip_bfloat16, 128,false, false><<<dim3(64, 2, 4), 256, 0, stream>>>(tex,  wsf + O_WG1,  b_g1,  nullptr, g1, 64);
  gate2_kernel<<<dim3(64, 4), 256, 0, stream>>>(g1, wsf + O_WG2, b_g2, labels, ci, out_cg, out_cond, wsf + O_INT);
  conv3x3_kernel<__hip_bfloat16, 128,true,  true ><<<dim3(64, 8, 4), 256, 0, stream>>>(tex,  wsf + O_WF1,  b_f1,  wsf + O_S, f1, 256);
  gemm_softmax_kernel<<<dim3(24, 1024), 256, 0, stream>>>(f1, w2bf, b_f2, wsf + O_INT, wts);

  dim3 dgrid(2, 32, 96), dblk(64, 4, 1);
  diff_kernel<<<dgrid, dblk, 0, stream>>>(depth, wts, ping);
  diff_kernel<<<dgrid, dblk, 0, stream>>>(ping, wts, pong);
  diff_kernel<<<dgrid, dblk, 0, stream>>>(pong, wts, ping);
  diff_kernel<<<dgrid, dblk, 0, stream>>>(ping, wts, pong);
  diff_kernel<<<dgrid, dblk, 0, stream>>>(pong, wts, ping);
  diff_kernel<<<dgrid, dblk, 0, stream>>>(ping, wts, pong);
  diff_kernel<<<dgrid, dblk, 0, stream>>>(pong, wts, ping);
  diff_kernel<<<dgrid, dblk, 0, stream>>>(ping, wts, out_enh);
}

// Round 7
// 789.974 us; speedup vs baseline: 4.5633x; 2.0353x over previous
//
#include <hip/hip_runtime.h>
#include <hip/hip_bf16.h>
#include <stdint.h>

#define DINL __device__ __forceinline__

DINL float bf2f(__hip_bfloat16 v) { return __bfloat162float(v); }
DINL __hip_bfloat16 f2bf(float v) { return __float2bfloat16(v); }
DINL float bflo(unsigned int u) { return __uint_as_float(u << 16); }
DINL float bfhi(unsigned int u) { return __uint_as_float(u & 0xffff0000u); }

DINL float loadf(float v) { return v; }
DINL float loadf(__hip_bfloat16 v) { return __bfloat162float(v); }

typedef __attribute__((ext_vector_type(8))) short bf16x8;
typedef __attribute__((ext_vector_type(4))) float f32x4;

// ---------------- ws layout ----------------
// fp32 region (float offsets):
#define O_WTE1 0         // [2][3][9][32] fp32 blocked (te1 VALU conv)   1728
#define O_WG2  1792      // [6][64]                                      384
#define O_SS   2304      // [4][256][9]  border-class emb sums           9216
#define O_INT  11520     // [4][16384] intensity                         65536
// fp32 region ends at float 77056 = byte 308224
// bf16/byte offsets:
#define BO_W2B   308224u   // w_f2  bf16 [24][64][256]          786432 B
#define BO_TE2B 1094656u   // w_te2 bf16 [2][2][9][64][32]      147456 B
#define BO_WG1B 1242112u   // w_g1  bf16 [1][4][9][64][32]      147456 B
#define BO_WF1B 1389568u   // w_f1  bf16 [4][4][9][64][32]      589824 B (ends 1979392)
#define BO_TEX  4194304u   // tex bf16 pixel-major [4][16384][128]  16.78 MB
#define BO_F1   20971520u  // f1  bf16 pixel-major [4][16384][256]  33.55 MB
#define BO_PING 54525952u  // fp32 [4*24*16384]  6.29 MB
#define BO_PONG 60817408u
#define BO_W    67108864u  // weights bf16 [4][24][49][16384]  154.14 MB
#define BO_T1   BO_W             // t1 bf16 pixel-major [4][16384][64] (dead before W written)
#define BO_G1   (BO_W + 16777216u)  // g1 bf16 pixel-major [4][16384][64] (dead before W written)

// ---------------- prep: weight re-layouts (bf16 MFMA blocks) + SS table ----------------
__global__ __launch_bounds__(256) void prep_kernel(
    const float* __restrict__ w_te1, const float* __restrict__ w_te2,
    const float* __restrict__ w_g1,  const float* __restrict__ w_f1,
    const float* __restrict__ w_f2,  const float* __restrict__ w_g2,
    const float* __restrict__ emb,   const int* __restrict__ labels,
    float* __restrict__ wsf)
{
  const int gid = blockIdx.x * 256 + threadIdx.x;
  const int stride = gridDim.x * 256;
  const int A0 = 1728, A1 = A0 + 393216, A2 = A1 + 73728, A3 = A2 + 73728,
            A4 = A3 + 294912, A5 = A4 + 384;
  __hip_bfloat16* w2b  = (__hip_bfloat16*)((char*)wsf + BO_W2B);
  __hip_bfloat16* te2b = (__hip_bfloat16*)((char*)wsf + BO_TE2B);
  __hip_bfloat16* g1b  = (__hip_bfloat16*)((char*)wsf + BO_WG1B);
  __hip_bfloat16* f1b  = (__hip_bfloat16*)((char*)wsf + BO_WF1B);
  for (int i = gid; i < A5; i += stride) {
    if (i < A0) {
      // te1 fp32 blocked [och/32][3][9][32]
      int s = i; int o = s / 27; int r = s - o * 27; int ic = r / 9; int t = r - ic * 9;
      wsf[O_WTE1 + (((o >> 5) * 3 + ic) * 9 + t) * 32 + (o & 31)] = w_te1[s];
    } else if (i < A1) {
      // w_f2 [1176][256] fp32 -> bf16 [24][64][256], taps 49..63 zero
      int s = i - A0;
      int k = s & 255; int t = (s >> 8) & 63; int c = s >> 14;
      float v = (t < 49) ? w_f2[(c * 49 + t) * 256 + k] : 0.f;
      w2b[s] = f2bf(v);
    } else if (i < A2) {
      // w_te2 [128][64][9] -> bf16 [ocg2][kc2][t9][n64][k32]
      int s = i - A1;
      int k = s & 31; int n = (s >> 5) & 63; int u = s >> 11;
      int t = u % 9; int v = u / 9; int kc = v & 1; int ocg = v >> 1;
      te2b[s] = f2bf(w_te2[((ocg * 64 + n) * 64 + kc * 32 + k) * 9 + t]);
    } else if (i < A3) {
      // w_g1 [64][128][9] -> bf16 [1][kc4][t9][n64][k32]
      int s = i - A2;
      int k = s & 31; int n = (s >> 5) & 63; int u = s >> 11;
      int t = u % 9; int kc = u / 9;
      g1b[s] = f2bf(w_g1[(n * 128 + kc * 32 + k) * 9 + t]);
    } else if (i < A4) {
      // w_f1 [256][256][9] (spatial half ich<128) -> bf16 [ocg4][kc4][t9][n64][k32]
      int s = i - A3;
      int k = s & 31; int n = (s >> 5) & 63; int u = s >> 11;
      int t = u % 9; int v = u / 9; int kc = v & 3; int ocg = v >> 2;
      f1b[s] = f2bf(w_f1[((ocg * 64 + n) * 256 + kc * 32 + k) * 9 + t]);
    } else {
      int s = i - A4;
      wsf[O_WG2 + s] = w_g2[s];
    }
  }
  // SS[b][o][class] = sum_t valid(class,t) * sum_i w_f1[o][128+i][t]*emb[lab_b][i]
  if (gid < 1024) {
    int b = gid >> 8, o = gid & 255;
    int lab = labels[b];
    float St[9];
#pragma unroll
    for (int t = 0; t < 9; ++t) St[t] = 0.f;
    for (int i = 0; i < 128; ++i) {
      float e = emb[lab * 128 + i];
#pragma unroll
      for (int t = 0; t < 9; ++t)
        St[t] += w_f1[(o * 256 + 128 + i) * 9 + t] * e;
    }
#pragma unroll
    for (int ch = 0; ch < 3; ++ch)
#pragma unroll
      for (int cw = 0; cw < 3; ++cw) {
        float sum = 0.f;
#pragma unroll
        for (int t = 0; t < 9; ++t) {
          int kh = t / 3, kw = t - kh * 3;
          bool ok = !(ch == 0 && kh == 0) && !(ch == 2 && kh == 2) &&
                    !(cw == 0 && kw == 0) && !(cw == 2 && kw == 2);
          if (ok) sum += St[t];
        }
        wsf[O_SS + gid * 9 + ch * 3 + cw] = sum;
      }
  }
}

// ---------------- small VALU 3x3 conv (te1 only: ICH=3) ----------------
template<typename TIn, int ICH, bool PIXMAJOR>
__global__ __launch_bounds__(256, 2) void conv3x3_kernel(
    const TIn* __restrict__ in, const float* __restrict__ wf,
    const float* __restrict__ bias,
    __hip_bfloat16* __restrict__ out, const int och_total)
{
  constexpr int CH = (ICH < 16) ? ICH : 16;
  constexpr int NCHUNK = ICH / CH;
  __shared__ TIn sIn[CH][18][20];
  const int tid = threadIdx.x;
  const int b = blockIdx.z;
  const int ob = blockIdx.y;
  const int och0 = ob * 32;
  const int tileY = blockIdx.x >> 3, tileX = blockIdx.x & 7;
  const int ty = tid >> 4, tx = tid & 15;
  const int h = tileY * 16 + ty, w = tileX * 16 + tx;
  const int h0 = tileY * 16 - 1, w0 = tileX * 16 - 1;

  float acc[32];
#pragma unroll
  for (int o = 0; o < 32; ++o) acc[o] = bias[och0 + o];

  for (int cc = 0; cc < NCHUNK; ++cc) {
    if (cc) __syncthreads();
    for (int e = tid; e < CH * 324; e += 256) {
      int ic = e / 324, r = e - ic * 324;
      int y = r / 18, x = r - y * 18;
      int gh = h0 + y, gw = w0 + x;
      TIn v = TIn(0.f);
      if ((unsigned)gh < 128u && (unsigned)gw < 128u)
        v = in[((b * ICH + cc * CH + ic) << 14) + (gh << 7) + gw];
      sIn[ic][y][x] = v;
    }
    __syncthreads();
#pragma unroll 1
    for (int ic = 0; ic < CH; ++ic) {
      const float* wrow = wf + (ob * ICH + cc * CH + ic) * 288;  // [9][32]
#pragma unroll
      for (int t = 0; t < 9; ++t) {
        const int kh = t / 3, kw = t - kh * 3;
        const float v = loadf(sIn[ic][ty + kh][tx + kw]);
#pragma unroll
        for (int o = 0; o < 32; ++o)
          acc[o] = fmaf(wrow[t * 32 + o], v, acc[o]);
      }
    }
  }

  const int pix = (h << 7) + w;
  if constexpr (!PIXMAJOR) {
#pragma unroll
    for (int o = 0; o < 32; ++o)
      out[((b * och_total + och0 + o) << 14) + pix] = f2bf(fmaxf(acc[o], 0.f));
  } else {
    union { uint4 u4[4]; __hip_bfloat16 hh[32]; } pk;
#pragma unroll
    for (int o = 0; o < 32; ++o) pk.hh[o] = f2bf(fmaxf(acc[o], 0.f));
    uint4* dst = reinterpret_cast<uint4*>(out + ((size_t)(b << 14) + pix) * och_total + och0);
#pragma unroll
    for (int i = 0; i < 4; ++i) dst[i] = pk.u4[i];
  }
}

// ---------------- MFMA implicit-GEMM 3x3 conv (zero pad), pixel-major bf16 ----------------
// in: [b][16384][ICH] bf16.  wb: [ocg][ICH/32][9][64][32] bf16.  out: [b][16384][och_total].
// Block: 16x16 pixel tile x 64 och. Wave w owns pixel rows w*4..w*4+3, all 4 n-tiles.
// Per k-chunk(32): halo 18x18x32 + weights 9x64x32 in LDS. Per tap: 4+4 ds_read_b128 : 16 MFMA.
// R6 bug (NaN): weight staging loop bound was 1152 uint4 — half the 9*64*32/8 = 2304 tile;
// taps 5..8 were unwritten LDS. Fixed to 2304.
template<int ICH, bool ADD_SS>
__global__ __launch_bounds__(256, 2) void conv3x3_mfma_kernel(
    const __hip_bfloat16* __restrict__ in, const __hip_bfloat16* __restrict__ wb,
    const float* __restrict__ bias, const float* __restrict__ SS,
    __hip_bfloat16* __restrict__ out, const int och_total)
{
  constexpr int NKC = ICH / 32;
  __shared__ __hip_bfloat16 sH[324][40];    // (y*18+x) halo pos x 32k
  __shared__ __hip_bfloat16 sW[9][64][40];  // tap x n(och) x 32k
  const int tid = threadIdx.x, b = blockIdx.z, ocg = blockIdx.y;
  const int tileY = blockIdx.x >> 3, tileX = blockIdx.x & 7;
  const int h0 = tileY * 16 - 1, w0 = tileX * 16 - 1;
  const int wave = tid >> 6, lane = tid & 63, m16 = lane & 15, quad = lane >> 4;

  f32x4 acc[4][4];
#pragma unroll
  for (int i = 0; i < 4; ++i)
#pragma unroll
    for (int j = 0; j < 4; ++j) acc[i][j] = f32x4{0.f, 0.f, 0.f, 0.f};

  for (int kc = 0; kc < NKC; ++kc) {
    if (kc) __syncthreads();
    // halo: 324 positions x 32 ch (4 uint4 each)
    for (int e = tid; e < 1296; e += 256) {
      int pos = e >> 2, q = e & 3;
      int y = pos / 18, x = pos - y * 18;
      int gh = h0 + y, gw = w0 + x;
      uint4 v = uint4{0u, 0u, 0u, 0u};
      if ((unsigned)gh < 128u && (unsigned)gw < 128u)
        v = *(const uint4*)(in + ((size_t)((b << 14) + (gh << 7) + gw)) * ICH + kc * 32 + q * 8);
      *(uint4*)&sH[pos][q * 8] = v;
    }
    // weights: 9*64*32 halves = 2304 uint4, contiguous in global
    const uint4* wsrc = (const uint4*)(wb + ((size_t)(ocg * NKC + kc)) * 9 * 64 * 32);
    for (int e = tid; e < 2304; e += 256) {
      int q = e & 3, n = (e >> 2) & 63, t = e >> 8;
      *(uint4*)&sW[t][n][q * 8] = wsrc[e];
    }
    __syncthreads();
#pragma unroll
    for (int t = 0; t < 9; ++t) {
      const int dy = t / 3, dx = t - dy * 3;
      bf16x8 bfr[4];
#pragma unroll
      for (int nt = 0; nt < 4; ++nt)
        bfr[nt] = *(const bf16x8*)&sW[t][nt * 16 + m16][quad * 8];
#pragma unroll
      for (int mi = 0; mi < 4; ++mi) {
        const int py = wave * 4 + mi;
        const bf16x8 afr = *(const bf16x8*)&sH[(py + dy) * 18 + dx + m16][quad * 8];
#pragma unroll
        for (int nt = 0; nt < 4; ++nt)
          acc[mi][nt] = __builtin_amdgcn_mfma_f32_16x16x32_bf16(afr, bfr[nt], acc[mi][nt], 0, 0, 0);
      }
    }
  }

  // epilogue: bias + (border-class emb term) + ReLU
  float bv[4];
#pragma unroll
  for (int nt = 0; nt < 4; ++nt) bv[nt] = bias[ocg * 64 + nt * 16 + m16];
#pragma unroll
  for (int mi = 0; mi < 4; ++mi) {
    const int py = wave * 4 + mi;
    const int h = tileY * 16 + py;
    const int chc = (h == 0) ? 0 : ((h == 127) ? 2 : 1);  // wave-uniform
#pragma unroll
    for (int nt = 0; nt < 4; ++nt) {
      float sr0 = 0.f, sr1 = 0.f, sr2 = 0.f;
      if constexpr (ADD_SS) {
        const float* sp = SS + ((size_t)(b << 8) + (ocg * 64 + nt * 16 + m16)) * 9;
        sr0 = sp[chc * 3 + 0]; sr1 = sp[chc * 3 + 1]; sr2 = sp[chc * 3 + 2];
      }
      const int och = ocg * 64 + nt * 16 + m16;
#pragma unroll
      for (int r = 0; r < 4; ++r) {
        const int px = quad * 4 + r;
        const int w = tileX * 16 + px;
        float v = acc[mi][nt][r] + bv[nt];
        if constexpr (ADD_SS)
          v += (w == 0) ? sr0 : ((w == 127) ? sr2 : sr1);
        v = fmaxf(v, 0.f);
        out[((size_t)((b << 14) + (h << 7) + w)) * och_total + och] = f2bf(v);
      }
    }
  }
}

// ---------------- gate 1x1 conv + sigmoid + class_gate / intensity / condition_map ----------------
__global__ __launch_bounds__(256) void gate2_kernel(
    const __hip_bfloat16* __restrict__ g1, const float* __restrict__ wg2,
    const float* __restrict__ b_g2, const int* __restrict__ labels,
    const float* __restrict__ ci,
    float* __restrict__ out_cg, float* __restrict__ out_cond,
    float* __restrict__ inten)
{
  const int b = blockIdx.y;
  const int pix = blockIdx.x * 256 + threadIdx.x;
  float acc[6];
#pragma unroll
  for (int k = 0; k < 6; ++k) acc[k] = b_g2[k];
  const uint4* gp = (const uint4*)(g1 + ((size_t)((b << 14) + pix)) * 64);
#pragma unroll
  for (int i4 = 0; i4 < 8; ++i4) {
    const uint4 q = gp[i4];
    const float v0 = bflo(q.x), v1 = bfhi(q.x), v2 = bflo(q.y), v3 = bfhi(q.y);
    const float v4 = bflo(q.z), v5 = bfhi(q.z), v6 = bflo(q.w), v7 = bfhi(q.w);
#pragma unroll
    for (int k = 0; k < 6; ++k) {
      const float* wr = wg2 + k * 64 + i4 * 8;
      acc[k] = fmaf(wr[0], v0, acc[k]); acc[k] = fmaf(wr[1], v1, acc[k]);
      acc[k] = fmaf(wr[2], v2, acc[k]); acc[k] = fmaf(wr[3], v3, acc[k]);
      acc[k] = fmaf(wr[4], v4, acc[k]); acc[k] = fmaf(wr[5], v5, acc[k]);
      acc[k] = fmaf(wr[6], v6, acc[k]); acc[k] = fmaf(wr[7], v7, acc[k]);
    }
  }
  const int lab = labels[b];
  float gate[6], gl = 0.f;
#pragma unroll
  for (int k = 0; k < 6; ++k) {
    gate[k] = 1.f / (1.f + __expf(-acc[k]));
    gl = (k == lab) ? gate[k] : gl;
  }
  const float civ = ci[lab];
  const float it = gl * civ;
#pragma unroll
  for (int k = 0; k < 6; ++k)
    out_cg[((b * 6 + k) << 14) + pix] = (k == lab) ? gate[k] : 0.f;
  inten[(b << 14) + pix] = it;
  out_cond[(b << 14) + pix] = it * gl;
}

// ---------------- fused MFMA GEMM (65536x1176x256) + intensity + softmax(49) ----------------
__global__ __launch_bounds__(256, 2) void gemm_softmax_kernel(
    const __hip_bfloat16* __restrict__ f1, const __hip_bfloat16* __restrict__ w2b,
    const float* __restrict__ b_f2, const float* __restrict__ inten,
    __hip_bfloat16* __restrict__ wout)
{
  __shared__ __hip_bfloat16 sA[64][264];   // 64 pixels x 256 K (+8 pad)
  __shared__ __hip_bfloat16 sB[64][264];   // 64 taps   x 256 K
  const int c = blockIdx.x;       // channel 0..23
  const int pix0 = blockIdx.y * 64;
  const int tid = threadIdx.x;

  {
    const uint4* srcA = (const uint4*)(f1 + (size_t)pix0 * 256);
    const uint4* srcB = (const uint4*)(w2b + (size_t)c * 64 * 256);
    for (int i = tid; i < 2048; i += 256) {
      int r = i >> 5, q = i & 31;
      *(uint4*)&sA[r][q * 8] = srcA[i];
      *(uint4*)&sB[r][q * 8] = srcB[i];
    }
  }
  __syncthreads();

  const int wave = tid >> 6, lane = tid & 63;
  const int m = lane & 15, quad = lane >> 4;
  f32x4 acc[4] = {f32x4{0,0,0,0}, f32x4{0,0,0,0}, f32x4{0,0,0,0}, f32x4{0,0,0,0}};
#pragma unroll
  for (int ks = 0; ks < 8; ++ks) {
    const int ko = ks * 32 + quad * 8;
    const bf16x8 bfr = *(const bf16x8*)&sB[wave * 16 + m][ko];
#pragma unroll
    for (int mt = 0; mt < 4; ++mt) {
      const bf16x8 afr = *(const bf16x8*)&sA[mt * 16 + m][ko];
      acc[mt] = __builtin_amdgcn_mfma_f32_16x16x32_bf16(afr, bfr, acc[mt], 0, 0, 0);
    }
  }
  __syncthreads();

  float* sL = (float*)&sB[0][0];   // [64 t][66 pix] logits
#pragma unroll
  for (int mt = 0; mt < 4; ++mt)
#pragma unroll
    for (int r = 0; r < 4; ++r)
      sL[(wave * 16 + m) * 66 + (mt * 16 + quad * 4 + r)] = acc[mt][r];
  __syncthreads();

  if (tid < 64) {
    const int P = pix0 + tid;
    const float s = inten[P];
    float mx = -3.4e38f;
    for (int t = 0; t < 49; ++t) {
      float v = (sL[t * 66 + tid] + b_f2[c * 49 + t]) * s;
      sL[t * 66 + tid] = v;
      mx = fmaxf(mx, v);
    }
    float sum = 0.f;
    for (int t = 0; t < 49; ++t) {
      float e = __expf(sL[t * 66 + tid] - mx);
      sL[t * 66 + tid] = e;
      sum += e;
    }
    const float rs = 1.f / sum;
    const int b = P >> 14, p = P & 16383;
    __hip_bfloat16* wo = wout + (((size_t)(b * 24 + c) * 49) << 14) + p;
    for (int t = 0; t < 49; ++t)
      wo[(size_t)t << 14] = f2bf(sL[t * 66 + tid] * rs);
  }
}

// ---------------- one diffusion step: per-pixel 7x7 weighted average, edge-clamped ----------------
__global__ __launch_bounds__(256) void diff_kernel(
    const float* __restrict__ lin, const __hip_bfloat16* __restrict__ wts,
    float* __restrict__ lout)
{
  __shared__ float sT[10][70];
  const int bc = blockIdx.z;
  const int w0 = blockIdx.x * 64, h0 = blockIdx.y * 4;
  const int tid = threadIdx.y * 64 + threadIdx.x;
  for (int e = tid; e < 700; e += 256) {
    int y = e / 70, x = e - y * 70;
    int gh = min(max(h0 - 3 + y, 0), 127), gw = min(max(w0 - 3 + x, 0), 127);
    sT[y][x] = lin[(bc << 14) + (gh << 7) + gw];
  }
  __syncthreads();
  const int tx = threadIdx.x, ty = threadIdx.y;
  const int pix = ((h0 + ty) << 7) + w0 + tx;
  const __hip_bfloat16* wp = wts + (((size_t)bc * 49) << 14) + pix;
  float acc = 0.f;
#pragma unroll
  for (int t = 0; t < 49; ++t) {
    const int kh = t / 7, kw = t - kh * 7;
    acc = fmaf(bf2f(wp[(size_t)t << 14]), sT[ty + kh][tx + kw], acc);
  }
  lout[(bc << 14) + pix] = acc;
}

// ---------------- orchestration ----------------
extern "C" void kernel_launch(void* const* d_in, const int* in_sizes, int n_in,
                              void* d_out, int out_size, void* d_ws, size_t ws_size,
                              hipStream_t stream)
{
  const float* depth = (const float*)d_in[0];
  const float* texf  = (const float*)d_in[1];
  const int*   labels= (const int*)d_in[2];
  const float* w_te1 = (const float*)d_in[3];
  const float* b_te1 = (const float*)d_in[4];
  const float* w_te2 = (const float*)d_in[5];
  const float* b_te2 = (const float*)d_in[6];
  const float* emb   = (const float*)d_in[7];
  const float* w_f1  = (const float*)d_in[8];
  const float* b_f1  = (const float*)d_in[9];
  const float* w_f2  = (const float*)d_in[10];
  const float* b_f2  = (const float*)d_in[11];
  const float* w_g1  = (const float*)d_in[12];
  const float* b_g1  = (const float*)d_in[13];
  const float* w_g2  = (const float*)d_in[14];
  const float* b_g2  = (const float*)d_in[15];
  const float* ci    = (const float*)d_in[16];

  char*  ws  = (char*)d_ws;
  float* wsf = (float*)d_ws;
  __hip_bfloat16* w2bf  = (__hip_bfloat16*)(ws + BO_W2B);
  __hip_bfloat16* te2bf = (__hip_bfloat16*)(ws + BO_TE2B);
  __hip_bfloat16* g1bf  = (__hip_bfloat16*)(ws + BO_WG1B);
  __hip_bfloat16* f1bf  = (__hip_bfloat16*)(ws + BO_WF1B);
  __hip_bfloat16* tex   = (__hip_bfloat16*)(ws + BO_TEX);
  __hip_bfloat16* f1    = (__hip_bfloat16*)(ws + BO_F1);
  float* ping           = (float*)(ws + BO_PING);
  float* pong           = (float*)(ws + BO_PONG);
  __hip_bfloat16* wts   = (__hip_bfloat16*)(ws + BO_W);
  __hip_bfloat16* t1    = (__hip_bfloat16*)(ws + BO_T1);
  __hip_bfloat16* g1    = (__hip_bfloat16*)(ws + BO_G1);

  float* out      = (float*)d_out;
  float* out_enh  = out;                 // [4][24][128][128]
  float* out_cg   = out + 1572864;       // [4][6][128][128]
  float* out_cond = out + 1966080;       // [4][1][128][128]

  prep_kernel<<<512, 256, 0, stream>>>(w_te1, w_te2, w_g1, w_f1, w_f2, w_g2, emb, labels, wsf);
  // te1: fp32 VALU conv, writes t1 pixel-major [pix][64]
  conv3x3_kernel<float, 3, true><<<dim3(64, 2, 4), 256, 0, stream>>>(texf, wsf + O_WTE1, b_te1, t1, 64);
  // te2 / gate1 / fusion: MFMA implicit-GEMM convs (pixel-major bf16)
  conv3x3_mfma_kernel<64,  false><<<dim3(64, 2, 4), 256, 0, stream>>>(t1,  te2bf, b_te2, nullptr,      tex, 128);
  conv3x3_mfma_kernel<128, false><<<dim3(64, 1, 4), 256, 0, stream>>>(tex, g1bf,  b_g1,  nullptr,      g1,  64);
  gate2_kernel<<<dim3(64, 4), 256, 0, stream>>>(g1, wsf + O_WG2, b_g2, labels, ci, out_cg, out_cond, wsf + O_INT);
  conv3x3_mfma_kernel<128, true ><<<dim3(64, 4, 4), 256, 0, stream>>>(tex, f1bf,  b_f1,  wsf + O_SS,   f1,  256);
  gemm_softmax_kernel<<<dim3(24, 1024), 256, 0, stream>>>(f1, w2bf, b_f2, wsf + O_INT, wts);

  dim3 dgrid(2, 32, 96), dblk(64, 4, 1);
  diff_kernel<<<dgrid, dblk, 0, stream>>>(depth, wts, ping);
  diff_kernel<<<dgrid, dblk, 0, stream>>>(ping, wts, pong);
  diff_kernel<<<dgrid, dblk, 0, stream>>>(pong, wts, ping);
  diff_kernel<<<dgrid, dblk, 0, stream>>>(ping, wts, pong);
  diff_kernel<<<dgrid, dblk, 0, stream>>>(pong, wts, ping);
  diff_kernel<<<dgrid, dblk, 0, stream>>>(ping, wts, pong);
  diff_kernel<<<dgrid, dblk, 0, stream>>>(pong, wts, ping);
  diff_kernel<<<dgrid, dblk, 0, stream>>>(ping, wts, out_enh);
}

// Round 8
// 608.707 us; speedup vs baseline: 5.9221x; 1.2978x over previous
//
#include <hip/hip_runtime.h>
#include <hip/hip_bf16.h>
#include <stdint.h>

#define DINL __device__ __forceinline__

DINL float bf2f(__hip_bfloat16 v) { return __bfloat162float(v); }
DINL __hip_bfloat16 f2bf(float v) { return __float2bfloat16(v); }
DINL float bflo(unsigned int u) { return __uint_as_float(u << 16); }
DINL float bfhi(unsigned int u) { return __uint_as_float(u & 0xffff0000u); }

DINL float loadf(float v) { return v; }
DINL float loadf(__hip_bfloat16 v) { return __bfloat162float(v); }

typedef __attribute__((ext_vector_type(8))) short bf16x8;
typedef __attribute__((ext_vector_type(4))) float f32x4;

// ---------------- ws layout ----------------
// fp32 region (float offsets):
#define O_WTE1 0         // [2][3][9][32] fp32 blocked (te1 VALU conv)   1728
#define O_WG2  1792      // [6][64]                                      384
#define O_SS   2304      // [4][256][9]  border-class emb sums           9216
#define O_INT  11520     // [4][16384] intensity                         65536
// fp32 region ends at float 77056 = byte 308224
// bf16/byte offsets:
#define BO_W2B   308224u   // w_f2 bf16 FRAGMENT layout [24][4][8][64][8]  786432 B
#define BO_TE2B 1094656u   // w_te2 bf16 [2][2][9][64][32]      147456 B
#define BO_WG1B 1242112u   // w_g1  bf16 [1][4][9][64][32]      147456 B
#define BO_WF1B 1389568u   // w_f1  bf16 [4][4][9][64][32]      589824 B (ends 1979392)
#define BO_TEX  4194304u   // tex bf16 pixel-major [4][16384][128]  16.78 MB
#define BO_F1   20971520u  // f1  bf16 pixel-major [4][16384][256]  33.55 MB
#define BO_PING 54525952u  // fp32 [4*24*16384]  6.29 MB
#define BO_PONG 60817408u
#define BO_W    67108864u  // weights bf16 [4][24][49][16384]  154.14 MB
#define BO_T1   BO_W             // t1 bf16 pixel-major [4][16384][64] (dead before W written)
#define BO_G1   (BO_W + 16777216u)  // g1 bf16 pixel-major [4][16384][64] (dead before W written)

// ---------------- prep: weight re-layouts (bf16 MFMA blocks) + SS table ----------------
__global__ __launch_bounds__(256) void prep_kernel(
    const float* __restrict__ w_te1, const float* __restrict__ w_te2,
    const float* __restrict__ w_g1,  const float* __restrict__ w_f1,
    const float* __restrict__ w_f2,  const float* __restrict__ w_g2,
    const float* __restrict__ emb,   const int* __restrict__ labels,
    float* __restrict__ wsf)
{
  const int gid = blockIdx.x * 256 + threadIdx.x;
  const int stride = gridDim.x * 256;
  const int A0 = 1728, A1 = A0 + 393216, A2 = A1 + 73728, A3 = A2 + 73728,
            A4 = A3 + 294912, A5 = A4 + 384;
  __hip_bfloat16* w2b  = (__hip_bfloat16*)((char*)wsf + BO_W2B);
  __hip_bfloat16* te2b = (__hip_bfloat16*)((char*)wsf + BO_TE2B);
  __hip_bfloat16* g1b  = (__hip_bfloat16*)((char*)wsf + BO_WG1B);
  __hip_bfloat16* f1b  = (__hip_bfloat16*)((char*)wsf + BO_WF1B);
  for (int i = gid; i < A5; i += stride) {
    if (i < A0) {
      // te1 fp32 blocked [och/32][3][9][32]
      int s = i; int o = s / 27; int r = s - o * 27; int ic = r / 9; int t = r - ic * 9;
      wsf[O_WTE1 + (((o >> 5) * 3 + ic) * 9 + t) * 32 + (o & 31)] = w_te1[s];
    } else if (i < A1) {
      // w_f2 [1176][256] fp32 -> bf16 MFMA B-fragment layout [c24][wv4][ks8][lane64][8]
      // value = W[tap = wv*16 + (lane&15)][k = ks*32 + (lane>>4)*8 + j], taps>=49 zero
      int s = i - A0;
      int j = s & 7; int lane = (s >> 3) & 63; int ks = (s >> 9) & 7;
      int wv = (s >> 12) & 3; int c = s >> 14;
      int tap = wv * 16 + (lane & 15);
      int k = ks * 32 + (lane >> 4) * 8 + j;
      float v = (tap < 49) ? w_f2[(c * 49 + tap) * 256 + k] : 0.f;
      w2b[s] = f2bf(v);
    } else if (i < A2) {
      // w_te2 [128][64][9] -> bf16 [ocg2][kc2][t9][n64][k32]
      int s = i - A1;
      int k = s & 31; int n = (s >> 5) & 63; int u = s >> 11;
      int t = u % 9; int v = u / 9; int kc = v & 1; int ocg = v >> 1;
      te2b[s] = f2bf(w_te2[((ocg * 64 + n) * 64 + kc * 32 + k) * 9 + t]);
    } else if (i < A3) {
      // w_g1 [64][128][9] -> bf16 [1][kc4][t9][n64][k32]
      int s = i - A2;
      int k = s & 31; int n = (s >> 5) & 63; int u = s >> 11;
      int t = u % 9; int kc = u / 9;
      g1b[s] = f2bf(w_g1[(n * 128 + kc * 32 + k) * 9 + t]);
    } else if (i < A4) {
      // w_f1 [256][256][9] (spatial half ich<128) -> bf16 [ocg4][kc4][t9][n64][k32]
      int s = i - A3;
      int k = s & 31; int n = (s >> 5) & 63; int u = s >> 11;
      int t = u % 9; int v = u / 9; int kc = v & 3; int ocg = v >> 2;
      f1b[s] = f2bf(w_f1[((ocg * 64 + n) * 256 + kc * 32 + k) * 9 + t]);
    } else {
      int s = i - A4;
      wsf[O_WG2 + s] = w_g2[s];
    }
  }
  // SS[b][o][class] = sum_t valid(class,t) * sum_i w_f1[o][128+i][t]*emb[lab_b][i]
  if (gid < 1024) {
    int b = gid >> 8, o = gid & 255;
    int lab = labels[b];
    float St[9];
#pragma unroll
    for (int t = 0; t < 9; ++t) St[t] = 0.f;
    for (int i = 0; i < 128; ++i) {
      float e = emb[lab * 128 + i];
#pragma unroll
      for (int t = 0; t < 9; ++t)
        St[t] += w_f1[(o * 256 + 128 + i) * 9 + t] * e;
    }
#pragma unroll
    for (int ch = 0; ch < 3; ++ch)
#pragma unroll
      for (int cw = 0; cw < 3; ++cw) {
        float sum = 0.f;
#pragma unroll
        for (int t = 0; t < 9; ++t) {
          int kh = t / 3, kw = t - kh * 3;
          bool ok = !(ch == 0 && kh == 0) && !(ch == 2 && kh == 2) &&
                    !(cw == 0 && kw == 0) && !(cw == 2 && kw == 2);
          if (ok) sum += St[t];
        }
        wsf[O_SS + gid * 9 + ch * 3 + cw] = sum;
      }
  }
}

// ---------------- small VALU 3x3 conv (te1 only: ICH=3) ----------------
template<typename TIn, int ICH, bool PIXMAJOR>
__global__ __launch_bounds__(256, 2) void conv3x3_kernel(
    const TIn* __restrict__ in, const float* __restrict__ wf,
    const float* __restrict__ bias,
    __hip_bfloat16* __restrict__ out, const int och_total)
{
  constexpr int CH = (ICH < 16) ? ICH : 16;
  constexpr int NCHUNK = ICH / CH;
  __shared__ TIn sIn[CH][18][20];
  const int tid = threadIdx.x;
  const int b = blockIdx.z;
  const int ob = blockIdx.y;
  const int och0 = ob * 32;
  const int tileY = blockIdx.x >> 3, tileX = blockIdx.x & 7;
  const int ty = tid >> 4, tx = tid & 15;
  const int h = tileY * 16 + ty, w = tileX * 16 + tx;
  const int h0 = tileY * 16 - 1, w0 = tileX * 16 - 1;

  float acc[32];
#pragma unroll
  for (int o = 0; o < 32; ++o) acc[o] = bias[och0 + o];

  for (int cc = 0; cc < NCHUNK; ++cc) {
    if (cc) __syncthreads();
    for (int e = tid; e < CH * 324; e += 256) {
      int ic = e / 324, r = e - ic * 324;
      int y = r / 18, x = r - y * 18;
      int gh = h0 + y, gw = w0 + x;
      TIn v = TIn(0.f);
      if ((unsigned)gh < 128u && (unsigned)gw < 128u)
        v = in[((b * ICH + cc * CH + ic) << 14) + (gh << 7) + gw];
      sIn[ic][y][x] = v;
    }
    __syncthreads();
#pragma unroll 1
    for (int ic = 0; ic < CH; ++ic) {
      const float* wrow = wf + (ob * ICH + cc * CH + ic) * 288;  // [9][32]
#pragma unroll
      for (int t = 0; t < 9; ++t) {
        const int kh = t / 3, kw = t - kh * 3;
        const float v = loadf(sIn[ic][ty + kh][tx + kw]);
#pragma unroll
        for (int o = 0; o < 32; ++o)
          acc[o] = fmaf(wrow[t * 32 + o], v, acc[o]);
      }
    }
  }

  const int pix = (h << 7) + w;
  if constexpr (!PIXMAJOR) {
#pragma unroll
    for (int o = 0; o < 32; ++o)
      out[((b * och_total + och0 + o) << 14) + pix] = f2bf(fmaxf(acc[o], 0.f));
  } else {
    union { uint4 u4[4]; __hip_bfloat16 hh[32]; } pk;
#pragma unroll
    for (int o = 0; o < 32; ++o) pk.hh[o] = f2bf(fmaxf(acc[o], 0.f));
    uint4* dst = reinterpret_cast<uint4*>(out + ((size_t)(b << 14) + pix) * och_total + och0);
#pragma unroll
    for (int i = 0; i < 4; ++i) dst[i] = pk.u4[i];
  }
}

// ---------------- MFMA implicit-GEMM 3x3 conv (zero pad), pixel-major bf16 ----------------
template<int ICH, bool ADD_SS>
__global__ __launch_bounds__(256, 2) void conv3x3_mfma_kernel(
    const __hip_bfloat16* __restrict__ in, const __hip_bfloat16* __restrict__ wb,
    const float* __restrict__ bias, const float* __restrict__ SS,
    __hip_bfloat16* __restrict__ out, const int och_total)
{
  constexpr int NKC = ICH / 32;
  __shared__ __hip_bfloat16 sH[324][40];    // (y*18+x) halo pos x 32k
  __shared__ __hip_bfloat16 sW[9][64][40];  // tap x n(och) x 32k
  const int tid = threadIdx.x, b = blockIdx.z, ocg = blockIdx.y;
  const int tileY = blockIdx.x >> 3, tileX = blockIdx.x & 7;
  const int h0 = tileY * 16 - 1, w0 = tileX * 16 - 1;
  const int wave = tid >> 6, lane = tid & 63, m16 = lane & 15, quad = lane >> 4;

  f32x4 acc[4][4];
#pragma unroll
  for (int i = 0; i < 4; ++i)
#pragma unroll
    for (int j = 0; j < 4; ++j) acc[i][j] = f32x4{0.f, 0.f, 0.f, 0.f};

  for (int kc = 0; kc < NKC; ++kc) {
    if (kc) __syncthreads();
    for (int e = tid; e < 1296; e += 256) {
      int pos = e >> 2, q = e & 3;
      int y = pos / 18, x = pos - y * 18;
      int gh = h0 + y, gw = w0 + x;
      uint4 v = uint4{0u, 0u, 0u, 0u};
      if ((unsigned)gh < 128u && (unsigned)gw < 128u)
        v = *(const uint4*)(in + ((size_t)((b << 14) + (gh << 7) + gw)) * ICH + kc * 32 + q * 8);
      *(uint4*)&sH[pos][q * 8] = v;
    }
    const uint4* wsrc = (const uint4*)(wb + ((size_t)(ocg * NKC + kc)) * 9 * 64 * 32);
    for (int e = tid; e < 2304; e += 256) {
      int q = e & 3, n = (e >> 2) & 63, t = e >> 8;
      *(uint4*)&sW[t][n][q * 8] = wsrc[e];
    }
    __syncthreads();
#pragma unroll
    for (int t = 0; t < 9; ++t) {
      const int dy = t / 3, dx = t - dy * 3;
      bf16x8 bfr[4];
#pragma unroll
      for (int nt = 0; nt < 4; ++nt)
        bfr[nt] = *(const bf16x8*)&sW[t][nt * 16 + m16][quad * 8];
#pragma unroll
      for (int mi = 0; mi < 4; ++mi) {
        const int py = wave * 4 + mi;
        const bf16x8 afr = *(const bf16x8*)&sH[(py + dy) * 18 + dx + m16][quad * 8];
#pragma unroll
        for (int nt = 0; nt < 4; ++nt)
          acc[mi][nt] = __builtin_amdgcn_mfma_f32_16x16x32_bf16(afr, bfr[nt], acc[mi][nt], 0, 0, 0);
      }
    }
  }

  float bv[4];
#pragma unroll
  for (int nt = 0; nt < 4; ++nt) bv[nt] = bias[ocg * 64 + nt * 16 + m16];
#pragma unroll
  for (int mi = 0; mi < 4; ++mi) {
    const int py = wave * 4 + mi;
    const int h = tileY * 16 + py;
    const int chc = (h == 0) ? 0 : ((h == 127) ? 2 : 1);
#pragma unroll
    for (int nt = 0; nt < 4; ++nt) {
      float sr0 = 0.f, sr1 = 0.f, sr2 = 0.f;
      if constexpr (ADD_SS) {
        const float* sp = SS + ((size_t)(b << 8) + (ocg * 64 + nt * 16 + m16)) * 9;
        sr0 = sp[chc * 3 + 0]; sr1 = sp[chc * 3 + 1]; sr2 = sp[chc * 3 + 2];
      }
      const int och = ocg * 64 + nt * 16 + m16;
#pragma unroll
      for (int r = 0; r < 4; ++r) {
        const int px = quad * 4 + r;
        const int w = tileX * 16 + px;
        float v = acc[mi][nt][r] + bv[nt];
        if constexpr (ADD_SS)
          v += (w == 0) ? sr0 : ((w == 127) ? sr2 : sr1);
        v = fmaxf(v, 0.f);
        out[((size_t)((b << 14) + (h << 7) + w)) * och_total + och] = f2bf(v);
      }
    }
  }
}

// ---------------- gate 1x1 conv + sigmoid + class_gate / intensity / condition_map ----------------
__global__ __launch_bounds__(256) void gate2_kernel(
    const __hip_bfloat16* __restrict__ g1, const float* __restrict__ wg2,
    const float* __restrict__ b_g2, const int* __restrict__ labels,
    const float* __restrict__ ci,
    float* __restrict__ out_cg, float* __restrict__ out_cond,
    float* __restrict__ inten)
{
  const int b = blockIdx.y;
  const int pix = blockIdx.x * 256 + threadIdx.x;
  float acc[6];
#pragma unroll
  for (int k = 0; k < 6; ++k) acc[k] = b_g2[k];
  const uint4* gp = (const uint4*)(g1 + ((size_t)((b << 14) + pix)) * 64);
#pragma unroll
  for (int i4 = 0; i4 < 8; ++i4) {
    const uint4 q = gp[i4];
    const float v0 = bflo(q.x), v1 = bfhi(q.x), v2 = bflo(q.y), v3 = bfhi(q.y);
    const float v4 = bflo(q.z), v5 = bfhi(q.z), v6 = bflo(q.w), v7 = bfhi(q.w);
#pragma unroll
    for (int k = 0; k < 6; ++k) {
      const float* wr = wg2 + k * 64 + i4 * 8;
      acc[k] = fmaf(wr[0], v0, acc[k]); acc[k] = fmaf(wr[1], v1, acc[k]);
      acc[k] = fmaf(wr[2], v2, acc[k]); acc[k] = fmaf(wr[3], v3, acc[k]);
      acc[k] = fmaf(wr[4], v4, acc[k]); acc[k] = fmaf(wr[5], v5, acc[k]);
      acc[k] = fmaf(wr[6], v6, acc[k]); acc[k] = fmaf(wr[7], v7, acc[k]);
    }
  }
  const int lab = labels[b];
  float gate[6], gl = 0.f;
#pragma unroll
  for (int k = 0; k < 6; ++k) {
    gate[k] = 1.f / (1.f + __expf(-acc[k]));
    gl = (k == lab) ? gate[k] : gl;
  }
  const float civ = ci[lab];
  const float it = gl * civ;
#pragma unroll
  for (int k = 0; k < 6; ++k)
    out_cg[((b * 6 + k) << 14) + pix] = (k == lab) ? gate[k] : 0.f;
  inten[(b << 14) + pix] = it;
  out_cond[(b << 14) + pix] = it * gl;
}

// ---------------- fused GEMM+softmax, v2 ----------------
// Block = 64 pixels x ALL 24 channels. A-fragments (channel-invariant) cached in
// 128 VGPRs, loaded once from global. B pre-packed in MFMA fragment order ->
// 8 global dwordx4 per wave per channel (L2-resident, no LDS/barriers on GEMM path).
// LDS = 49x65 fp32 logit tile only; softmax parallel over all 256 threads
// (4 threads/pixel x ~13 taps, two 4-way LDS reductions). 3 barriers/channel.
__global__ __launch_bounds__(256, 2) void gemm_softmax_kernel(
    const __hip_bfloat16* __restrict__ f1, const __hip_bfloat16* __restrict__ w2b,
    const float* __restrict__ b_f2, const float* __restrict__ inten,
    __hip_bfloat16* __restrict__ wout)
{
  __shared__ float sL[49 * 65];   // [tap][pix], stride 65 (odd dw: 2-way max on writes)
  __shared__ float sR1[256];      // max partials [tq][pix]
  __shared__ float sR2[256];      // sum partials [tq][pix]
  const int tid = threadIdx.x;
  const int pix0 = blockIdx.x * 64;
  const int wave = tid >> 6, lane = tid & 63;
  const int m16 = lane & 15, quad = lane >> 4;

  // ---- A fragments: 4 m-tiles x 8 k-steps, cached in registers for all 24 channels
  bf16x8 afr[4][8];
#pragma unroll
  for (int mt = 0; mt < 4; ++mt)
#pragma unroll
    for (int ks = 0; ks < 8; ++ks)
      afr[mt][ks] = *(const bf16x8*)(f1 + ((size_t)(pix0 + mt * 16 + m16)) * 256 + ks * 32 + quad * 8);

  // ---- epilogue thread mapping (fixed per block)
  const int epix = tid & 63, tq = tid >> 6;
  const int P = pix0 + epix;
  const float s = inten[P];
  const int ob = P >> 14, op = P & 16383;

  // logit-lane constants
  const int ltap = wave * 16 + m16;              // tap this lane writes (valid < 49)
  const int lpixb = quad * 4;                    // + r + mt*16 = pixel column

  for (int c = 0; c < 24; ++c) {
    // B fragments for (c, wave): 8 x dwordx4, fragment-ordered
    const bf16x8* bp = (const bf16x8*)(w2b + (((size_t)(c * 4 + wave) * 8) * 64 + lane) * 8);
    bf16x8 bfr[8];
#pragma unroll
    for (int ks = 0; ks < 8; ++ks) bfr[ks] = bp[ks * 64];

    f32x4 acc[4] = {f32x4{0,0,0,0}, f32x4{0,0,0,0}, f32x4{0,0,0,0}, f32x4{0,0,0,0}};
#pragma unroll
    for (int ks = 0; ks < 8; ++ks)
#pragma unroll
      for (int mt = 0; mt < 4; ++mt)
        acc[mt] = __builtin_amdgcn_mfma_f32_16x16x32_bf16(afr[mt][ks], bfr[ks], acc[mt], 0, 0, 0);

    // logits -> LDS (bias added here); prev channel's pass1 reads are fenced by B3 below
    const float bias_t = b_f2[c * 49 + min(ltap, 48)];
    if (ltap < 49) {
#pragma unroll
      for (int mt = 0; mt < 4; ++mt)
#pragma unroll
        for (int r = 0; r < 4; ++r)
          sL[ltap * 65 + mt * 16 + lpixb + r] = acc[mt][r] + bias_t;
    }
    __syncthreads();   // B1: logits visible

    // pass1: scaled max over my ~13 taps
    float v[13];
    float mx = -3.4e38f;
#pragma unroll
    for (int i = 0; i < 13; ++i) {
      const int t = tq * 13 + i;
      if (t < 49) { v[i] = sL[t * 65 + epix] * s; mx = fmaxf(mx, v[i]); }
    }
    sR1[tq * 64 + epix] = mx;
    __syncthreads();   // B2: max partials visible
    mx = fmaxf(fmaxf(sR1[epix], sR1[64 + epix]), fmaxf(sR1[128 + epix], sR1[192 + epix]));

    // pass2: exp + local sum (values stay in registers)
    float sum = 0.f;
#pragma unroll
    for (int i = 0; i < 13; ++i) {
      const int t = tq * 13 + i;
      if (t < 49) { v[i] = __expf(v[i] - mx); sum += v[i]; }
    }
    sR2[tq * 64 + epix] = sum;
    __syncthreads();   // B3: sum partials visible (also fences pass1 sL reads)
    const float tot = sR2[epix] + sR2[64 + epix] + sR2[128 + epix] + sR2[192 + epix];
    const float rs = 1.f / tot;

    __hip_bfloat16* wo = wout + (((size_t)(ob * 24 + c) * 49) << 14) + op;
#pragma unroll
    for (int i = 0; i < 13; ++i) {
      const int t = tq * 13 + i;
      if (t < 49) wo[(size_t)t << 14] = f2bf(v[i] * rs);
    }
  }
}

// ---------------- one diffusion step: per-pixel 7x7 weighted average, edge-clamped ----------------
__global__ __launch_bounds__(256) void diff_kernel(
    const float* __restrict__ lin, const __hip_bfloat16* __restrict__ wts,
    float* __restrict__ lout)
{
  __shared__ float sT[10][70];
  const int bc = blockIdx.z;
  const int w0 = blockIdx.x * 64, h0 = blockIdx.y * 4;
  const int tid = threadIdx.y * 64 + threadIdx.x;
  for (int e = tid; e < 700; e += 256) {
    int y = e / 70, x = e - y * 70;
    int gh = min(max(h0 - 3 + y, 0), 127), gw = min(max(w0 - 3 + x, 0), 127);
    sT[y][x] = lin[(bc << 14) + (gh << 7) + gw];
  }
  __syncthreads();
  const int tx = threadIdx.x, ty = threadIdx.y;
  const int pix = ((h0 + ty) << 7) + w0 + tx;
  const __hip_bfloat16* wp = wts + (((size_t)bc * 49) << 14) + pix;
  float acc = 0.f;
#pragma unroll
  for (int t = 0; t < 49; ++t) {
    const int kh = t / 7, kw = t - kh * 7;
    acc = fmaf(bf2f(wp[(size_t)t << 14]), sT[ty + kh][tx + kw], acc);
  }
  lout[(bc << 14) + pix] = acc;
}

// ---------------- orchestration ----------------
extern "C" void kernel_launch(void* const* d_in, const int* in_sizes, int n_in,
                              void* d_out, int out_size, void* d_ws, size_t ws_size,
                              hipStream_t stream)
{
  const float* depth = (const float*)d_in[0];
  const float* texf  = (const float*)d_in[1];
  const int*   labels= (const int*)d_in[2];
  const float* w_te1 = (const float*)d_in[3];
  const float* b_te1 = (const float*)d_in[4];
  const float* w_te2 = (const float*)d_in[5];
  const float* b_te2 = (const float*)d_in[6];
  const float* emb   = (const float*)d_in[7];
  const float* w_f1  = (const float*)d_in[8];
  const float* b_f1  = (const float*)d_in[9];
  const float* w_f2  = (const float*)d_in[10];
  const float* b_f2  = (const float*)d_in[11];
  const float* w_g1  = (const float*)d_in[12];
  const float* b_g1  = (const float*)d_in[13];
  const float* w_g2  = (const float*)d_in[14];
  const float* b_g2  = (const float*)d_in[15];
  const float* ci    = (const float*)d_in[16];

  char*  ws  = (char*)d_ws;
  float* wsf = (float*)d_ws;
  __hip_bfloat16* w2bf  = (__hip_bfloat16*)(ws + BO_W2B);
  __hip_bfloat16* te2bf = (__hip_bfloat16*)(ws + BO_TE2B);
  __hip_bfloat16* g1bf  = (__hip_bfloat16*)(ws + BO_WG1B);
  __hip_bfloat16* f1bf  = (__hip_bfloat16*)(ws + BO_WF1B);
  __hip_bfloat16* tex   = (__hip_bfloat16*)(ws + BO_TEX);
  __hip_bfloat16* f1    = (__hip_bfloat16*)(ws + BO_F1);
  float* ping           = (float*)(ws + BO_PING);
  float* pong           = (float*)(ws + BO_PONG);
  __hip_bfloat16* wts   = (__hip_bfloat16*)(ws + BO_W);
  __hip_bfloat16* t1    = (__hip_bfloat16*)(ws + BO_T1);
  __hip_bfloat16* g1    = (__hip_bfloat16*)(ws + BO_G1);

  float* out      = (float*)d_out;
  float* out_enh  = out;                 // [4][24][128][128]
  float* out_cg   = out + 1572864;       // [4][6][128][128]
  float* out_cond = out + 1966080;       // [4][1][128][128]

  prep_kernel<<<512, 256, 0, stream>>>(w_te1, w_te2, w_g1, w_f1, w_f2, w_g2, emb, labels, wsf);
  conv3x3_kernel<float, 3, true><<<dim3(64, 2, 4), 256, 0, stream>>>(texf, wsf + O_WTE1, b_te1, t1, 64);
  conv3x3_mfma_kernel<64,  false><<<dim3(64, 2, 4), 256, 0, stream>>>(t1,  te2bf, b_te2, nullptr,      tex, 128);
  conv3x3_mfma_kernel<128, false><<<dim3(64, 1, 4), 256, 0, stream>>>(tex, g1bf,  b_g1,  nullptr,      g1,  64);
  gate2_kernel<<<dim3(64, 4), 256, 0, stream>>>(g1, wsf + O_WG2, b_g2, labels, ci, out_cg, out_cond, wsf + O_INT);
  conv3x3_mfma_kernel<128, true ><<<dim3(64, 4, 4), 256, 0, stream>>>(tex, f1bf,  b_f1,  wsf + O_SS,   f1,  256);
  gemm_softmax_kernel<<<dim3(1024), 256, 0, stream>>>(f1, w2bf, b_f2, wsf + O_INT, wts);

  dim3 dgrid(2, 32, 96), dblk(64, 4, 1);
  diff_kernel<<<dgrid, dblk, 0, stream>>>(depth, wts, ping);
  diff_kernel<<<dgrid, dblk, 0, stream>>>(ping, wts, pong);
  diff_kernel<<<dgrid, dblk, 0, stream>>>(pong, wts, ping);
  diff_kernel<<<dgrid, dblk, 0, stream>>>(ping, wts, pong);
  diff_kernel<<<dgrid, dblk, 0, stream>>>(pong, wts, ping);
  diff_kernel<<<dgrid, dblk, 0, stream>>>(ping, wts, pong);
  diff_kernel<<<dgrid, dblk, 0, stream>>>(pong, wts, ping);
  diff_kernel<<<dgrid, dblk, 0, stream>>>(ping, wts, out_enh);
}